// Round 7
// baseline (18222.272 us; speedup 1.0000x reference)
//
#include <hip/hip_runtime.h>
#include <hip/hip_bf16.h>

// LSTMOutputProj: 2-layer LSTM (H=1024) over 128 sequential steps, BT=512 rows.
// Persistent kernel. 8 INTRA-XCD groups: each XCD owns 64 rows, worked by 32
// blocks of 1024 threads (1 per CU, runtime XCC_ID claim). All h exchange stays
// inside one XCD's L2 -> NO fences, weights stay L2/MALL-cached.
//   - h stores: global_store sc0 (write-through L1 -> L2, ack at vmcnt)
//   - h loads:  global_load  sc0 (bypass stale per-CU L1, hit fresh L2), 8-wide
//               outputs EARLY-CLOBBER ("=&v") so they can never alias the
//               address pair (R6 fault: output aliased addr under pressure)
//   - barrier:  vmcnt(0) + syncthreads + per-group atomic counter (same-XCD)
// Block = 64 rows x 32 gate-cols, 16 waves = 4 row-tiles x 2 col-halves x
// 2 gate-pairs (gp0: i,f + epilogue; gp1: g,o -> LDS handoff). 16 waves/CU
// doubles outstanding L2-fill concurrency vs the 8-wave round-4 kernel.

#define G4     4096
#define NSTEPS 128
#define NOUTC  33

typedef __attribute__((ext_vector_type(8))) short s8v;
typedef __attribute__((ext_vector_type(4))) float f4v;
typedef unsigned int u32;
typedef unsigned long long u64;

__device__ __forceinline__ float fsig(float x)  { return 1.0f / (1.0f + __expf(-x)); }
__device__ __forceinline__ float ftanh(float x) { return 2.0f / (1.0f + __expf(-2.0f * x)) - 1.0f; }

__device__ __forceinline__ short f2bf(float x) {
  union { __hip_bfloat16 b; short s; } u; u.b = __float2bfloat16(x); return u.s;
}
__device__ __forceinline__ float bf2f(short s) {
  union { __hip_bfloat16 b; short v; } u; u.v = s; return __bfloat162float(u.b);
}

// 8 x 16B loads, L1-bypass (sc0), stride 64B; one vmcnt(0) for the batch.
// "=&v" early-clobber: outputs must NOT alias the address register pair.
__device__ __forceinline__ void ld8_sc0(const short* p, s8v* d) {
  asm volatile(
      "global_load_dwordx4 %0, %8, off sc0\n\t"
      "global_load_dwordx4 %1, %8, off offset:64 sc0\n\t"
      "global_load_dwordx4 %2, %8, off offset:128 sc0\n\t"
      "global_load_dwordx4 %3, %8, off offset:192 sc0\n\t"
      "global_load_dwordx4 %4, %8, off offset:256 sc0\n\t"
      "global_load_dwordx4 %5, %8, off offset:320 sc0\n\t"
      "global_load_dwordx4 %6, %8, off offset:384 sc0\n\t"
      "global_load_dwordx4 %7, %8, off offset:448 sc0\n\t"
      "s_waitcnt vmcnt(0)"
      : "=&v"(d[0]), "=&v"(d[1]), "=&v"(d[2]), "=&v"(d[3]),
        "=&v"(d[4]), "=&v"(d[5]), "=&v"(d[6]), "=&v"(d[7])
      : "v"(p)
      : "memory");
}

// 8B coherent store (write-through L1 -> L2)
__device__ __forceinline__ void st8_sc0(short* p, u64 v) {
  asm volatile("global_store_dwordx2 %0, %1, off sc0" :: "v"(p), "v"(v) : "memory");
}

// ---------------- intra-XCD group barrier (no cache maintenance) --------------
__device__ __forceinline__ void gridbar(u32* bar, u32 target) {
  asm volatile("s_waitcnt vmcnt(0)" ::: "memory");
  __syncthreads();
  if (threadIdx.x == 0) {
    __hip_atomic_fetch_add(bar, 1u, __ATOMIC_RELAXED, __HIP_MEMORY_SCOPE_AGENT);
    while (__hip_atomic_load(bar, __ATOMIC_RELAXED, __HIP_MEMORY_SCOPE_AGENT) < target) {
      __builtin_amdgcn_s_sleep(1);
    }
  }
  __syncthreads();
}

// ---------------- precompute: transpose -> fragment-linearized bf16 -----------
__global__ __launch_bounds__(256) void transpose_frag_kernel(
    const float* __restrict__ src, short* __restrict__ dst_hi,
    short* __restrict__ dst_lo, int NK, int koff) {
  __shared__ float St[64][65];
  int n0 = (blockIdx.x & 63) * 64;
  int k0 = (blockIdx.x >> 6) * 64;
  int t = threadIdx.x;
  int nl = t & 63, kl = t >> 6;
#pragma unroll
  for (int it = 0; it < 16; ++it) {
    int k = kl + it * 4;
    St[k][nl] = src[(size_t)(k0 + k) * 4096 + n0 + nl];
  }
  __syncthreads();
  int lane = t & 63, w = t >> 6;
  for (int it = 0; it < 2; ++it) {
    int sub = it * 4 + w;  // 0..7 : 4 ntiles x 2 kchunks
    int nt = sub >> 1, kc = sub & 1;
    int nloc = nt * 16 + (lane & 15);
    int kbase = kc * 32 + (lane >> 4) * 8;
    float v[8];
#pragma unroll
    for (int ii = 0; ii < 8; ++ii) v[ii] = St[kbase + ii][nloc];
    s8v hv;
#pragma unroll
    for (int ii = 0; ii < 8; ++ii) hv[ii] = f2bf(v[ii]);
    size_t ntg = (size_t)(n0 / 16 + nt);
    size_t kcg = (size_t)(k0 / 32 + kc + koff);
    size_t off = (ntg * (size_t)NK + kcg) * 512 + (size_t)lane * 8;
    *(s8v*)(dst_hi + off) = hv;
    if (dst_lo) {
      s8v lv;
#pragma unroll
      for (int ii = 0; ii < 8; ++ii) lv[ii] = f2bf(v[ii] - bf2f(hv[ii]));
      *(s8v*)(dst_lo + off) = lv;
    }
  }
}

// ---------------- precompute: cond = x @ Wc + bc  (fp32, split to bf16 hi/lo) -
__global__ __launch_bounds__(256) void cond_kernel(
    const float* __restrict__ x, const float* __restrict__ Wc,
    const float* __restrict__ bc, short* __restrict__ cond_hi,
    short* __restrict__ cond_lo) {
  __shared__ float xs[8][512];
  int rb = (blockIdx.x >> 2) * 8;
  int cb = (blockIdx.x & 3) * 256;
  int t = threadIdx.x;
  for (int i = t; i < 8 * 512; i += 256)
    xs[i >> 9][i & 511] = x[(size_t)(rb + (i >> 9)) * 512 + (i & 511)];
  __syncthreads();
  float acc[8] = {0, 0, 0, 0, 0, 0, 0, 0};
  for (int k = 0; k < 512; ++k) {
    float w = Wc[(size_t)k * 1024 + cb + t];
#pragma unroll
    for (int rr = 0; rr < 8; ++rr) acc[rr] += xs[rr][k] * w;
  }
  float bcv = bc[cb + t];
#pragma unroll
  for (int rr = 0; rr < 8; ++rr) {
    float v = acc[rr] + bcv;
    short hi = f2bf(v);
    cond_hi[(size_t)(rb + rr) * 1024 + cb + t] = hi;
    cond_lo[(size_t)(rb + rr) * 1024 + cb + t] = f2bf(v - bf2f(hi));
  }
}

// ---------------- precompute: vec0, Wf, b1vec ---------------------------------
__global__ __launch_bounds__(256) void vecs_kernel(
    const float* __restrict__ Wih0, const float* __restrict__ bi,
    const float* __restrict__ Wi, const float* __restrict__ bih0,
    const float* __restrict__ bhh0, const float* __restrict__ bih1,
    const float* __restrict__ bhh1, float* __restrict__ vec0,
    float* __restrict__ Wf, float* __restrict__ b1vec) {
  int n = blockIdx.x * 256 + threadIdx.x;  // 0..4095
  float v0 = 0.f, w0 = 0.f, w1 = 0.f;
  for (int k = 0; k < 1024; ++k) {
    float w = Wih0[(size_t)k * 4096 + n];
    v0 += bi[k] * w;
    w0 += Wi[k] * w;
    w1 += Wi[1024 + k] * w;
  }
  vec0[n] = v0 + bih0[n] + bhh0[n];
  Wf[2 * n + 0] = w0;
  Wf[2 * n + 1] = w1;
  b1vec[n] = bih1[n] + bhh1[n];
}

// ---------------- precompute: Wo -> fragment-linearized bf16 hi/lo, N=48 pad --
__global__ __launch_bounds__(64) void wof_kernel(const float* __restrict__ Wo,
                                                 short* __restrict__ hi,
                                                 short* __restrict__ lo) {
  int nt = blockIdx.x >> 5;   // 0..2
  int kc = blockIdx.x & 31;   // 0..31
  int lane = threadIdx.x;     // 0..63
  int ch = nt * 16 + (lane & 15);
  int kb = kc * 32 + (lane >> 4) * 8;
  s8v hv, lv;
#pragma unroll
  for (int ii = 0; ii < 8; ++ii) {
    float v = (ch < NOUTC) ? Wo[(size_t)(kb + ii) * NOUTC + ch] : 0.f;
    short h = f2bf(v);
    hv[ii] = h;
    lv[ii] = f2bf(v - bf2f(h));
  }
  size_t off = ((size_t)(nt * 32 + kc)) * 512 + (size_t)lane * 8;
  *(s8v*)(hi + off) = hv;
  *(s8v*)(lo + off) = lv;
}

// ---------------- precompute: const0 = cond @ Wih0[H:] + vec0  (split bf16) ---
__global__ __launch_bounds__(512) void const0_kernel(
    const short* __restrict__ cond_hi, const short* __restrict__ cond_lo,
    const short* __restrict__ WTc_hi, const short* __restrict__ WTc_lo,
    const float* __restrict__ vec0, float* __restrict__ const0) {
  int j = blockIdx.x & 63, i = blockIdx.x >> 6;
  int w = threadIdx.x >> 6, lane = threadIdx.x & 63;
  int quad = lane >> 4, l16 = lane & 15;
  int rowA = i * 128 + w * 16 + l16;
  int rowC = i * 128 + w * 16 + quad * 4;
  int hid = j * 16 + l16;
  const short* ah = cond_hi + (size_t)rowA * 1024 + quad * 8;
  const short* al = cond_lo + (size_t)rowA * 1024 + quad * 8;
  f4v acc[4];
#pragma unroll
  for (int g = 0; g < 4; ++g) acc[g] = (f4v){0.f, 0.f, 0.f, 0.f};
#pragma unroll 2
  for (int kk = 0; kk < 32; ++kk) {
    s8v avh = *(const s8v*)(ah + kk * 32);
    s8v avl = *(const s8v*)(al + kk * 32);
#pragma unroll
    for (int g = 0; g < 4; ++g) {
      size_t off = ((size_t)(g * 64 + j) * 32 + kk) * 512 + (size_t)lane * 8;
      s8v bh = *(const s8v*)(WTc_hi + off);
      s8v bl = *(const s8v*)(WTc_lo + off);
      acc[g] = __builtin_amdgcn_mfma_f32_16x16x32_bf16(avh, bh, acc[g], 0, 0, 0);
      acc[g] = __builtin_amdgcn_mfma_f32_16x16x32_bf16(avh, bl, acc[g], 0, 0, 0);
      acc[g] = __builtin_amdgcn_mfma_f32_16x16x32_bf16(avl, bh, acc[g], 0, 0, 0);
    }
  }
#pragma unroll
  for (int g = 0; g < 4; ++g) {
    float vv = vec0[g * 1024 + hid];
#pragma unroll
    for (int p = 0; p < 4; ++p) {
      int r = rowC + p;
      const0[(size_t)r * G4 + g * 1024 + hid] = acc[g][p] + vv;
    }
  }
}

// ---------------- one logits tile (16 channels, or channel 32 for t==2) -------
__device__ __forceinline__ void logits_tile1(
    const short* __restrict__ ah, const short* __restrict__ WoFh,
    const short* __restrict__ WoFl, int lane, int t, int quad, int l16,
    float boA, float (*lt)[34]) {
  f4v la = {0.f, 0.f, 0.f, 0.f};
  const short* bh = WoFh + (size_t)t * 32 * 512 + (size_t)lane * 8;
  const short* bl = WoFl + (size_t)t * 32 * 512 + (size_t)lane * 8;
  s8v af[8];
  for (int kb = 0; kb < 4; ++kb) {
    ld8_sc0(ah + kb * 256, af);
#pragma unroll
    for (int kk = 0; kk < 8; ++kk) {
      int kg = kb * 8 + kk;
      la = __builtin_amdgcn_mfma_f32_16x16x32_bf16(af[kk], *(const s8v*)(bh + (size_t)kg * 512), la, 0, 0, 0);
      la = __builtin_amdgcn_mfma_f32_16x16x32_bf16(af[kk], *(const s8v*)(bl + (size_t)kg * 512), la, 0, 0, 0);
    }
  }
  int r0 = quad * 4;
#pragma unroll
  for (int p = 0; p < 4; ++p) {
    if (t == 0)      lt[r0 + p][l16]      = la[p] + boA;
    else if (t == 1) lt[r0 + p][16 + l16] = la[p] + boA;
    else if (l16 == 0) lt[r0 + p][32]     = la[p] + boA;
  }
}

// ---------------- main persistent kernel --------------------------------------
__global__ __launch_bounds__(1024) void lstm_main(
    const short* __restrict__ WT0, const short* __restrict__ WT1,
    const float* __restrict__ const0, const float* __restrict__ Wf,
    const float* __restrict__ b1vec, const short* __restrict__ WoFh,
    const short* __restrict__ WoFl, const float* __restrict__ bo,
    const float* __restrict__ sos, float* __restrict__ out,
    short* __restrict__ hbuf, u32* __restrict__ bar) {
  int tid = threadIdx.x;
  // which XCD am I on?  (HW_REG_XCC_ID = hwreg 20, verified on MI355X)
  u32 xcc;
  asm volatile("s_getreg_b32 %0, hwreg(20, 0, 32)" : "=s"(xcc));
  xcc &= 7;
  __shared__ u32 sslot;
  if (tid == 0)
    sslot = __hip_atomic_fetch_add(&bar[xcc], 1u, __ATOMIC_RELAXED,
                                   __HIP_MEMORY_SCOPE_AGENT);
  __syncthreads();
  u32 jb = sslot;
  if (jb >= 32) return;  // surplus block on a full XCD
  u32* gbar = bar + 64 + (size_t)xcc * 64;

  int w = tid >> 6, lane = tid & 63;
  int rt = w & 3;                          // row-tile 0..3
  int q = w >> 2;                          // 0..3
  int ch = q & 1;                          // col half (ntile) 0..1
  int gp = q >> 1;                         // gate pair: 0 -> i,f ; 1 -> g,o
  int lg = gp * 2 + ch;                    // logits tile id (3 = idle)
  int quad = lane >> 4, l16 = lane & 15;
  int quad8 = quad * 8;
  int R0g = (int)xcc * 64;                 // group's first row
  int rowA = R0g + rt * 16 + l16;          // A-fragment row
  int rowC = R0g + rt * 16 + quad * 4;     // C/D + epilogue base row
  int hid = (int)jb * 32 + ch * 16 + l16;  // h/gate column

  __shared__ float lgl[4][16][34];         // per-row-tile logits
  __shared__ short hst[4][2][16][20];      // per-(rt,ch) h repack
  __shared__ float accst[4][2][2][64][4];  // gp1 -> gp0 gate-partial handoff

  // step-invariant per-thread loads
  float wfv[4][2], b1v[4], c0v[4][4];
  size_t nb0[2], nb1[2];
#pragma unroll
  for (int g = 0; g < 4; ++g) {
    wfv[g][0] = Wf[(g * 1024 + hid) * 2 + 0];
    wfv[g][1] = Wf[(g * 1024 + hid) * 2 + 1];
    b1v[g] = b1vec[g * 1024 + hid];
#pragma unroll
    for (int p = 0; p < 4; ++p)
      c0v[g][p] = const0[(size_t)(rowC + p) * G4 + g * 1024 + hid];
  }
#pragma unroll
  for (int gg = 0; gg < 2; ++gg) {
    int nt = (gp * 2 + gg) * 64 + (int)jb * 2 + ch;
    nb0[gg] = (size_t)nt * 32;
    nb1[gg] = (size_t)nt * 64;
  }
  float boA = (lg == 0) ? bo[l16] : ((lg == 1) ? bo[16 + l16] : bo[32]);
  float sos0 = sos[0], sos1 = sos[1];
  float c0s[4] = {0.f, 0.f, 0.f, 0.f};
  float c1s[4] = {0.f, 0.f, 0.f, 0.f};
  float cu0[4], cu1[4];

  int rr = lane >> 2;       // repack row
  int cg = (lane & 3) * 4;  // repack col group (4 shorts = 8B)
  u32 snum = 0;

  for (int s = 0; s < NSTEPS; ++s) {
    int bank_r = (s & 1) * 2048;
    int bank_w = ((s + 1) & 1) * 2048;

    // ---- Phase 1a: logits(s-1) + cur(s-1), local ----
    if (s == 0) {
#pragma unroll
      for (int p = 0; p < 4; ++p) { cu0[p] = sos0; cu1[p] = sos1; }
    } else {
      const short* ah1 = hbuf + (size_t)rowA * G4 + bank_r + 1024 + quad8;
      if (lg < 3)
        logits_tile1(ah1, WoFh, WoFl, lane, lg, quad, l16, boA, lgl[rt]);
      __syncthreads();
      if (tid < 2 * NOUTC) {  // block jb outputs group rows 2jb, 2jb+1
        int rloc = (tid >= NOUTC) ? 1 : 0;
        int chn = tid - rloc * NOUTC;
        int rl = (int)jb * 2 + rloc;
        float v = lgl[rl >> 4][rl & 15][chn];
        int r = R0g + rl;
        out[((size_t)((r >> 6) * NOUTC + chn) * 64 + (r & 63)) * 128 + (s - 1)] = v;
      }
#pragma unroll
      for (int p = 0; p < 4; ++p) {
        int rl = quad * 4 + p;
        cu0[p] = (lgl[rt][rl][0] > 0.0f) ? 1.0f : 0.0f;
        float mx = lgl[rt][rl][1];
        int mi = 0;
        for (int v = 1; v < 32; ++v) {
          float t = lgl[rt][rl][1 + v];
          if (t > mx) { mx = t; mi = v; }
        }
        cu1[p] = (float)mi * (1.0f / 31.0f);
      }
    }

    // ---- Phase 1b: layer 0  g0 = h0_prev @ Whh0 + const0 + cur@Wf ----
    {
      f4v acc[2];
      acc[0] = (f4v){0.f, 0.f, 0.f, 0.f};
      acc[1] = (f4v){0.f, 0.f, 0.f, 0.f};
      if (s > 0) {  // h0_prev == 0 at s==0
        const short* ap = hbuf + (size_t)rowA * G4 + bank_r + quad8;
        s8v af[8];
        for (int kb = 0; kb < 4; ++kb) {
          ld8_sc0(ap + kb * 256, af);
#pragma unroll
          for (int kk = 0; kk < 8; ++kk) {
            int kg = kb * 8 + kk;
#pragma unroll
            for (int gg = 0; gg < 2; ++gg) {
              s8v bv = *(const s8v*)(WT0 + (nb0[gg] + kg) * 512 + (size_t)lane * 8);
              acc[gg] = __builtin_amdgcn_mfma_f32_16x16x32_bf16(af[kk], bv, acc[gg], 0, 0, 0);
            }
          }
        }
      }
      if (gp == 1) {
#pragma unroll
        for (int gg = 0; gg < 2; ++gg)
#pragma unroll
          for (int p = 0; p < 4; ++p) accst[rt][ch][gg][lane][p] = acc[gg][p];
      }
      __syncthreads();
      if (gp == 0) {
#pragma unroll
        for (int p = 0; p < 4; ++p) {
          float gi = acc[0][p] + c0v[0][p] + cu0[p] * wfv[0][0] + cu1[p] * wfv[0][1];
          float gf = acc[1][p] + c0v[1][p] + cu0[p] * wfv[1][0] + cu1[p] * wfv[1][1];
          float gg = accst[rt][ch][0][lane][p] + c0v[2][p] + cu0[p] * wfv[2][0] + cu1[p] * wfv[2][1];
          float go = accst[rt][ch][1][lane][p] + c0v[3][p] + cu0[p] * wfv[3][0] + cu1[p] * wfv[3][1];
          float cc = fsig(gf) * c0s[p] + fsig(gi) * ftanh(gg);
          c0s[p] = cc;
          hst[rt][ch][quad * 4 + p][l16] = f2bf(fsig(go) * ftanh(cc));
        }
        u64 v = *(const u64*)&hst[rt][ch][rr][cg];
        st8_sc0(hbuf + (size_t)(R0g + rt * 16 + rr) * G4 + bank_w +
                    (int)jb * 32 + ch * 16 + cg, v);
      }
    }
    ++snum; gridbar(gbar, snum * 32u);

    // ---- Phase 2: layer 1  g1 = h0_new @ Wih1 + h1_prev @ Whh1 + b1 ----
    {
      f4v acc[2];
      acc[0] = (f4v){0.f, 0.f, 0.f, 0.f};
      acc[1] = (f4v){0.f, 0.f, 0.f, 0.f};
      const short* ap0 = hbuf + (size_t)rowA * G4 + bank_w + quad8;  // h0 new
      s8v af[8];
      for (int kb = 0; kb < 4; ++kb) {
        ld8_sc0(ap0 + kb * 256, af);
#pragma unroll
        for (int kk = 0; kk < 8; ++kk) {
          int kg = kb * 8 + kk;
#pragma unroll
          for (int gg = 0; gg < 2; ++gg) {
            s8v bv = *(const s8v*)(WT1 + (nb1[gg] + kg) * 512 + (size_t)lane * 8);
            acc[gg] = __builtin_amdgcn_mfma_f32_16x16x32_bf16(af[kk], bv, acc[gg], 0, 0, 0);
          }
        }
      }
      if (s > 0) {  // h1_prev == 0 at s==0
        const short* ap1 = hbuf + (size_t)rowA * G4 + bank_r + 1024 + quad8;
        for (int kb = 0; kb < 4; ++kb) {
          ld8_sc0(ap1 + kb * 256, af);
#pragma unroll
          for (int kk = 0; kk < 8; ++kk) {
            int kg = kb * 8 + kk;
#pragma unroll
            for (int gg = 0; gg < 2; ++gg) {
              s8v bv = *(const s8v*)(WT1 + (nb1[gg] + 32 + kg) * 512 + (size_t)lane * 8);
              acc[gg] = __builtin_amdgcn_mfma_f32_16x16x32_bf16(af[kk], bv, acc[gg], 0, 0, 0);
            }
          }
        }
      }
      if (gp == 1) {
#pragma unroll
        for (int gg = 0; gg < 2; ++gg)
#pragma unroll
          for (int p = 0; p < 4; ++p) accst[rt][ch][gg][lane][p] = acc[gg][p];
      }
      __syncthreads();
      if (gp == 0) {
#pragma unroll
        for (int p = 0; p < 4; ++p) {
          float gi = acc[0][p] + b1v[0];
          float gf = acc[1][p] + b1v[1];
          float gg = accst[rt][ch][0][lane][p] + b1v[2];
          float go = accst[rt][ch][1][lane][p] + b1v[3];
          float cc = fsig(gf) * c1s[p] + fsig(gi) * ftanh(gg);
          c1s[p] = cc;
          hst[rt][ch][quad * 4 + p][l16] = f2bf(fsig(go) * ftanh(cc));
        }
        u64 v = *(const u64*)&hst[rt][ch][rr][cg];
        st8_sc0(hbuf + (size_t)(R0g + rt * 16 + rr) * G4 + bank_w + 1024 +
                    (int)jb * 32 + ch * 16 + cg, v);
      }
    }
    ++snum; gridbar(gbar, snum * 32u);
  }

  // final logits for s=127 (h1(127) is in bank 0)
  {
    const short* ah1 = hbuf + (size_t)rowA * G4 + 0 + 1024 + quad8;
    if (lg < 3)
      logits_tile1(ah1, WoFh, WoFl, lane, lg, quad, l16, boA, lgl[rt]);
    __syncthreads();
    if (tid < 2 * NOUTC) {
      int rloc = (tid >= NOUTC) ? 1 : 0;
      int chn = tid - rloc * NOUTC;
      int rl = (int)jb * 2 + rloc;
      float v = lgl[rl >> 4][rl & 15][chn];
      int r = R0g + rl;
      out[((size_t)((r >> 6) * NOUTC + chn) * 64 + (r & 63)) * 128 + (NSTEPS - 1)] = v;
    }
  }
}

// ---------------- host launch -------------------------------------------------
extern "C" void kernel_launch(void* const* d_in, const int* in_sizes, int n_in,
                              void* d_out, int out_size, void* d_ws, size_t ws_size,
                              hipStream_t stream) {
  (void)in_sizes; (void)n_in; (void)out_size; (void)ws_size;
  const float* x    = (const float*)d_in[0];
  const float* sos  = (const float*)d_in[1];
  const float* Wc   = (const float*)d_in[2];
  const float* bc   = (const float*)d_in[3];
  const float* Wi   = (const float*)d_in[4];
  const float* bi   = (const float*)d_in[5];
  const float* Wih0 = (const float*)d_in[6];
  const float* Whh0 = (const float*)d_in[7];
  const float* bih0 = (const float*)d_in[8];
  const float* bhh0 = (const float*)d_in[9];
  const float* Wih1 = (const float*)d_in[10];
  const float* Whh1 = (const float*)d_in[11];
  const float* bih1 = (const float*)d_in[12];
  const float* bhh1 = (const float*)d_in[13];
  const float* Wo   = (const float*)d_in[14];
  const float* bo   = (const float*)d_in[15];
  float* out = (float*)d_out;

  char* p = (char*)d_ws;
  short* WT0    = (short*)p; p += (size_t)256 * 32 * 512 * 2;  // 8 MB
  short* WT1    = (short*)p; p += (size_t)256 * 64 * 512 * 2;  // 16 MB
  short* WTc_hi = (short*)p; p += (size_t)256 * 32 * 512 * 2;  // 8 MB
  short* WTc_lo = (short*)p; p += (size_t)256 * 32 * 512 * 2;  // 8 MB
  float* const0 = (float*)p; p += (size_t)512 * 4096 * 4;      // 8 MB
  short* hbuf   = (short*)p; p += (size_t)512 * 4096 * 2;      // 4 MB
  short* cond_hi= (short*)p; p += (size_t)512 * 1024 * 2;      // 1 MB
  short* cond_lo= (short*)p; p += (size_t)512 * 1024 * 2;      // 1 MB
  float* vec0   = (float*)p; p += 4096 * 4;
  float* Wf     = (float*)p; p += 4096 * 2 * 4;
  float* b1vec  = (float*)p; p += 4096 * 4;
  short* WoFh   = (short*)p; p += (size_t)48 * 1024 * 2;       // 96 KB
  short* WoFl   = (short*)p; p += (size_t)48 * 1024 * 2;       // 96 KB
  u32*   bar    = (u32*)p;   p += 4096;  // [0..7] XCD slot counters; +64: group barriers

  hipMemsetAsync(bar, 0, 4096, stream);

  transpose_frag_kernel<<<1024, 256, 0, stream>>>(Whh0, WT0, nullptr, 32, 0);
  transpose_frag_kernel<<<1024, 256, 0, stream>>>(Wih1, WT1, nullptr, 64, 0);
  transpose_frag_kernel<<<1024, 256, 0, stream>>>(Whh1, WT1, nullptr, 64, 32);
  transpose_frag_kernel<<<1024, 256, 0, stream>>>(Wih0 + (size_t)1024 * 4096,
                                                  WTc_hi, WTc_lo, 32, 0);
  cond_kernel<<<256, 256, 0, stream>>>(x, Wc, bc, cond_hi, cond_lo);
  vecs_kernel<<<16, 256, 0, stream>>>(Wih0, bi, Wi, bih0, bhh0, bih1, bhh1,
                                      vec0, Wf, b1vec);
  wof_kernel<<<96, 64, 0, stream>>>(Wo, WoFh, WoFl);
  const0_kernel<<<256, 512, 0, stream>>>(cond_hi, cond_lo, WTc_hi, WTc_lo,
                                         vec0, const0);
  lstm_main<<<1024, 1024, 0, stream>>>(WT0, WT1, const0, Wf, b1vec, WoFh, WoFl,
                                       bo, sos, out, hbuf, bar);
}

// Round 8
// 7219.366 us; speedup vs baseline: 2.5241x; 2.5241x over previous
//
#include <hip/hip_runtime.h>
#include <hip/hip_bf16.h>

// LSTMOutputProj: 2-layer LSTM (H=1024), 128 steps, BT=512 rows.
// COLUMN-PARTITIONED persistent kernel: XCD x owns hidden cols x*128..x*128+127
// (all 4 gates, both layers). Weight slice = 3 MB -> permanently L2-resident
// (weight fetch ~0). 32 blocks/XCD (runtime XCC claim), block jb owns rows
// jb*16..jb*16+15 for the XCD's col slice.
// Cross-XCD h exchange through the MALL:
//   - h writes: RETURNING system-scope atomic exchange (executes AT the MALL;
//     returned value proves completion at the coherent point), returns kept
//     live via asm sink, drained by vmcnt(0) before barrier arrival.
//   - h reads: system-scope bypass loads (staged once per block into LDS,
//     shared by all 8 waves -> no duplicate MALL reads).
//   - barrier: global 256-arrival counter, system scope. NO fences ever ->
//     L2 weight residency preserved.
// Numerics: identical MFMA chains / accumulation order / epilogue expression
// trees as the round-4 kernel -> bit-identical output.

#define G4     4096
#define NSTEPS 128
#define NOUTC  33

typedef __attribute__((ext_vector_type(8))) short s8v;
typedef __attribute__((ext_vector_type(4))) float f4v;
typedef unsigned int u32;
typedef unsigned long long u64;

__device__ __forceinline__ float fsig(float x)  { return 1.0f / (1.0f + __expf(-x)); }
__device__ __forceinline__ float ftanh(float x) { return 2.0f / (1.0f + __expf(-2.0f * x)) - 1.0f; }

__device__ __forceinline__ short f2bf(float x) {
  union { __hip_bfloat16 b; short s; } u; u.b = __float2bfloat16(x); return u.s;
}
__device__ __forceinline__ float bf2f(short s) {
  union { __hip_bfloat16 b; short v; } u; u.v = s; return __bfloat162float(u.b);
}

// ---------------- global barrier (no cache maintenance) -----------------------
__device__ __forceinline__ void gridbar(u32* bar, u32 target) {
  asm volatile("s_waitcnt vmcnt(0)" ::: "memory");  // drain swaps (returns back)
  __syncthreads();
  if (threadIdx.x == 0) {
    __hip_atomic_fetch_add(bar, 1u, __ATOMIC_RELAXED, __HIP_MEMORY_SCOPE_SYSTEM);
    while (__hip_atomic_load(bar, __ATOMIC_RELAXED, __HIP_MEMORY_SCOPE_SYSTEM) < target) {
      __builtin_amdgcn_s_sleep(1);
    }
  }
  __syncthreads();
}

// ---------------- stage 16 rows x 1024 bf16 of h from MALL into LDS -----------
__device__ __forceinline__ void stage16(short (*dst)[1032], const short* hbuf,
                                        int row0, int bankoff, int tid) {
#pragma unroll
  for (int i = 0; i < 8; ++i) {
    int q = tid * 8 + i;          // 0..4095 u64 chunks (16 rows x 256)
    int row = q >> 8, c4 = q & 255;
    const u64* src = (const u64*)(hbuf + (size_t)(row0 + row) * G4 + bankoff) + c4;
    u64 v = __hip_atomic_load(src, __ATOMIC_RELAXED, __HIP_MEMORY_SCOPE_SYSTEM);
    *(u64*)&dst[row][c4 * 4] = v;
  }
}

// ---------------- precompute: transpose -> fragment-linearized bf16 -----------
__global__ __launch_bounds__(256) void transpose_frag_kernel(
    const float* __restrict__ src, short* __restrict__ dst_hi,
    short* __restrict__ dst_lo, int NK, int koff) {
  __shared__ float St[64][65];
  int n0 = (blockIdx.x & 63) * 64;
  int k0 = (blockIdx.x >> 6) * 64;
  int t = threadIdx.x;
  int nl = t & 63, kl = t >> 6;
#pragma unroll
  for (int it = 0; it < 16; ++it) {
    int k = kl + it * 4;
    St[k][nl] = src[(size_t)(k0 + k) * 4096 + n0 + nl];
  }
  __syncthreads();
  int lane = t & 63, w = t >> 6;
  for (int it = 0; it < 2; ++it) {
    int sub = it * 4 + w;  // 0..7 : 4 ntiles x 2 kchunks
    int nt = sub >> 1, kc = sub & 1;
    int nloc = nt * 16 + (lane & 15);
    int kbase = kc * 32 + (lane >> 4) * 8;
    float v[8];
#pragma unroll
    for (int ii = 0; ii < 8; ++ii) v[ii] = St[kbase + ii][nloc];
    s8v hv;
#pragma unroll
    for (int ii = 0; ii < 8; ++ii) hv[ii] = f2bf(v[ii]);
    size_t ntg = (size_t)(n0 / 16 + nt);
    size_t kcg = (size_t)(k0 / 32 + kc + koff);
    size_t off = (ntg * (size_t)NK + kcg) * 512 + (size_t)lane * 8;
    *(s8v*)(dst_hi + off) = hv;
    if (dst_lo) {
      s8v lv;
#pragma unroll
      for (int ii = 0; ii < 8; ++ii) lv[ii] = f2bf(v[ii] - bf2f(hv[ii]));
      *(s8v*)(dst_lo + off) = lv;
    }
  }
}

// ---------------- precompute: cond = x @ Wc + bc  (fp32, split to bf16 hi/lo) -
__global__ __launch_bounds__(256) void cond_kernel(
    const float* __restrict__ x, const float* __restrict__ Wc,
    const float* __restrict__ bc, short* __restrict__ cond_hi,
    short* __restrict__ cond_lo) {
  __shared__ float xs[8][512];
  int rb = (blockIdx.x >> 2) * 8;
  int cb = (blockIdx.x & 3) * 256;
  int t = threadIdx.x;
  for (int i = t; i < 8 * 512; i += 256)
    xs[i >> 9][i & 511] = x[(size_t)(rb + (i >> 9)) * 512 + (i & 511)];
  __syncthreads();
  float acc[8] = {0, 0, 0, 0, 0, 0, 0, 0};
  for (int k = 0; k < 512; ++k) {
    float w = Wc[(size_t)k * 1024 + cb + t];
#pragma unroll
    for (int rr = 0; rr < 8; ++rr) acc[rr] += xs[rr][k] * w;
  }
  float bcv = bc[cb + t];
#pragma unroll
  for (int rr = 0; rr < 8; ++rr) {
    float v = acc[rr] + bcv;
    short hi = f2bf(v);
    cond_hi[(size_t)(rb + rr) * 1024 + cb + t] = hi;
    cond_lo[(size_t)(rb + rr) * 1024 + cb + t] = f2bf(v - bf2f(hi));
  }
}

// ---------------- precompute: vec0, Wf, b1vec ---------------------------------
__global__ __launch_bounds__(256) void vecs_kernel(
    const float* __restrict__ Wih0, const float* __restrict__ bi,
    const float* __restrict__ Wi, const float* __restrict__ bih0,
    const float* __restrict__ bhh0, const float* __restrict__ bih1,
    const float* __restrict__ bhh1, float* __restrict__ vec0,
    float* __restrict__ Wf, float* __restrict__ b1vec) {
  int n = blockIdx.x * 256 + threadIdx.x;  // 0..4095
  float v0 = 0.f, w0 = 0.f, w1 = 0.f;
  for (int k = 0; k < 1024; ++k) {
    float w = Wih0[(size_t)k * 4096 + n];
    v0 += bi[k] * w;
    w0 += Wi[k] * w;
    w1 += Wi[1024 + k] * w;
  }
  vec0[n] = v0 + bih0[n] + bhh0[n];
  Wf[2 * n + 0] = w0;
  Wf[2 * n + 1] = w1;
  b1vec[n] = bih1[n] + bhh1[n];
}

// ---------------- precompute: Wo -> fragment-linearized bf16 hi/lo, N=48 pad --
__global__ __launch_bounds__(64) void wof_kernel(const float* __restrict__ Wo,
                                                 short* __restrict__ hi,
                                                 short* __restrict__ lo) {
  int nt = blockIdx.x >> 5;   // 0..2
  int kc = blockIdx.x & 31;   // 0..31
  int lane = threadIdx.x;     // 0..63
  int ch = nt * 16 + (lane & 15);
  int kb = kc * 32 + (lane >> 4) * 8;
  s8v hv, lv;
#pragma unroll
  for (int ii = 0; ii < 8; ++ii) {
    float v = (ch < NOUTC) ? Wo[(size_t)(kb + ii) * NOUTC + ch] : 0.f;
    short h = f2bf(v);
    hv[ii] = h;
    lv[ii] = f2bf(v - bf2f(h));
  }
  size_t off = ((size_t)(nt * 32 + kc)) * 512 + (size_t)lane * 8;
  *(s8v*)(hi + off) = hv;
  *(s8v*)(lo + off) = lv;
}

// ---------------- precompute: const0 = cond @ Wih0[H:] + vec0  (split bf16) ---
__global__ __launch_bounds__(512) void const0_kernel(
    const short* __restrict__ cond_hi, const short* __restrict__ cond_lo,
    const short* __restrict__ WTc_hi, const short* __restrict__ WTc_lo,
    const float* __restrict__ vec0, float* __restrict__ const0) {
  int j = blockIdx.x & 63, i = blockIdx.x >> 6;
  int w = threadIdx.x >> 6, lane = threadIdx.x & 63;
  int quad = lane >> 4, l16 = lane & 15;
  int rowA = i * 128 + w * 16 + l16;
  int rowC = i * 128 + w * 16 + quad * 4;
  int hid = j * 16 + l16;
  const short* ah = cond_hi + (size_t)rowA * 1024 + quad * 8;
  const short* al = cond_lo + (size_t)rowA * 1024 + quad * 8;
  f4v acc[4];
#pragma unroll
  for (int g = 0; g < 4; ++g) acc[g] = (f4v){0.f, 0.f, 0.f, 0.f};
#pragma unroll 2
  for (int kk = 0; kk < 32; ++kk) {
    s8v avh = *(const s8v*)(ah + kk * 32);
    s8v avl = *(const s8v*)(al + kk * 32);
#pragma unroll
    for (int g = 0; g < 4; ++g) {
      size_t off = ((size_t)(g * 64 + j) * 32 + kk) * 512 + (size_t)lane * 8;
      s8v bh = *(const s8v*)(WTc_hi + off);
      s8v bl = *(const s8v*)(WTc_lo + off);
      acc[g] = __builtin_amdgcn_mfma_f32_16x16x32_bf16(avh, bh, acc[g], 0, 0, 0);
      acc[g] = __builtin_amdgcn_mfma_f32_16x16x32_bf16(avh, bl, acc[g], 0, 0, 0);
      acc[g] = __builtin_amdgcn_mfma_f32_16x16x32_bf16(avl, bh, acc[g], 0, 0, 0);
    }
  }
#pragma unroll
  for (int g = 0; g < 4; ++g) {
    float vv = vec0[g * 1024 + hid];
#pragma unroll
    for (int p = 0; p < 4; ++p) {
      int r = rowC + p;
      const0[(size_t)r * G4 + g * 1024 + hid] = acc[g][p] + vv;
    }
  }
}

// ---------------- main persistent kernel --------------------------------------
__global__ __launch_bounds__(512) void lstm_main(
    const short* __restrict__ WT0, const short* __restrict__ WT1,
    const float* __restrict__ const0, const float* __restrict__ Wf,
    const float* __restrict__ b1vec, const short* __restrict__ WoFh,
    const short* __restrict__ WoFl, const float* __restrict__ bo,
    const float* __restrict__ sos, float* __restrict__ out,
    short* __restrict__ hbuf, u32* __restrict__ bar) {
  int tid = threadIdx.x;
  u32 xcc;
  asm volatile("s_getreg_b32 %0, hwreg(20, 0, 32)" : "=s"(xcc));
  xcc &= 7;
  __shared__ u32 sslot;
  if (tid == 0)
    sslot = __hip_atomic_fetch_add(&bar[xcc], 1u, __ATOMIC_RELAXED,
                                   __HIP_MEMORY_SCOPE_SYSTEM);
  __syncthreads();
  u32 jb = sslot;
  if (jb >= 32) return;          // surplus block on a full XCD
  u32* gbar = bar + 64;          // single global barrier counter (256 arrivals)

  int w = tid >> 6, lane = tid & 63;
  int g = w >> 1, half = w & 1;  // wave -> gate g, ntile-half
  int quad = lane >> 4, l16 = lane & 15;
  int quad8 = quad * 8;
  int x = (int)xcc;
  int row0 = (int)jb * 16;       // block's 16 rows (same rows on every XCD)
  int erow = tid >> 5;           // epilogue: row within block (0..15)
  int ecb  = (tid & 31) * 4;     // epilogue: col base within slice (0..124)
  int gr = row0 + erow;          // global row of epilogue cells

  __shared__ short Ast[16][1032];   // staged A (h0_prev / h0_new), +8 pad
  __shared__ short Bst[16][1032];   // staged h1_prev
  __shared__ float accst[4][16][128];  // gate partials: [gate][row][col]
  __shared__ float lgl[16][34];
  __shared__ float curs[16][2];

  // step-invariant per-thread constants (epilogue cells: 1 row x 4 cols)
  float wf0v[4][4], wf1v[4][4], b1vv[4][4], c0vv[4][4];
#pragma unroll
  for (int g2 = 0; g2 < 4; ++g2)
#pragma unroll
    for (int cc = 0; cc < 4; ++cc) {
      int n = g2 * 1024 + x * 128 + ecb + cc;
      wf0v[g2][cc] = Wf[2 * n + 0];
      wf1v[g2][cc] = Wf[2 * n + 1];
      b1vv[g2][cc] = b1vec[n];
      c0vv[g2][cc] = const0[(size_t)gr * G4 + n];
    }
  size_t nb0[4], nb1[4];
#pragma unroll
  for (int j = 0; j < 4; ++j) {
    int nt = g * 64 + x * 8 + half * 4 + j;  // global ntile of this wave's j-th tile
    nb0[j] = (size_t)nt * 32;
    nb1[j] = (size_t)nt * 64;
  }
  float boA = (w == 0) ? bo[l16] : ((w == 1) ? bo[16 + l16] : bo[32]);
  float sos0 = sos[0], sos1 = sos[1];
  float c0s[4] = {0.f, 0.f, 0.f, 0.f};
  float c1s[4] = {0.f, 0.f, 0.f, 0.f};
  u64 sink = 0;
  u32 snum = 0;

  for (int s = 0; s < NSTEPS; ++s) {
    int bank_r = (s & 1) * 2048;
    int bank_w = ((s + 1) & 1) * 2048;

    // ================= Phase A: logits+cur (s-1) and layer-0 =================
    if (s > 0) {
      stage16(Ast, hbuf, row0, bank_r, tid);         // h0_prev rows
      stage16(Bst, hbuf, row0, bank_r + 1024, tid);  // h1_prev rows
      asm volatile("s_waitcnt vmcnt(0)" ::: "memory");
      __syncthreads();
      if (w < 3) {  // logits: 3 waves, one Wo ntile each (hi/lo interleave)
        f4v la = {0.f, 0.f, 0.f, 0.f};
        const short* bh = WoFh + (size_t)w * 32 * 512 + (size_t)lane * 8;
        const short* bl = WoFl + (size_t)w * 32 * 512 + (size_t)lane * 8;
#pragma unroll 4
        for (int kk = 0; kk < 32; ++kk) {
          s8v av = *(const s8v*)&Bst[l16][quad8 + kk * 32];
          la = __builtin_amdgcn_mfma_f32_16x16x32_bf16(av, *(const s8v*)(bh + (size_t)kk * 512), la, 0, 0, 0);
          la = __builtin_amdgcn_mfma_f32_16x16x32_bf16(av, *(const s8v*)(bl + (size_t)kk * 512), la, 0, 0, 0);
        }
        int r0 = quad * 4;
#pragma unroll
        for (int p = 0; p < 4; ++p) {
          if (w == 0)      lgl[r0 + p][l16]      = la[p] + boA;
          else if (w == 1) lgl[r0 + p][16 + l16] = la[p] + boA;
          else if (l16 == 0) lgl[r0 + p][32]     = la[p] + boA;
        }
      }
    }
    // layer-0 gemm: g0 = h0_prev @ Whh0 (K=1024) for this wave's 4 ntiles
    {
      f4v acc[4];
#pragma unroll
      for (int j = 0; j < 4; ++j) acc[j] = (f4v){0.f, 0.f, 0.f, 0.f};
      if (s > 0) {
#pragma unroll 4
        for (int kk = 0; kk < 32; ++kk) {
          s8v av = *(const s8v*)&Ast[l16][quad8 + kk * 32];
#pragma unroll
          for (int j = 0; j < 4; ++j) {
            s8v bv = *(const s8v*)(WT0 + (nb0[j] + kk) * 512 + (size_t)lane * 8);
            acc[j] = __builtin_amdgcn_mfma_f32_16x16x32_bf16(av, bv, acc[j], 0, 0, 0);
          }
        }
      }
#pragma unroll
      for (int j = 0; j < 4; ++j)
#pragma unroll
        for (int p = 0; p < 4; ++p)
          accst[g][quad * 4 + p][(half * 4 + j) * 16 + l16] = acc[j][p];
    }
    __syncthreads();
    if (s > 0) {
      if (tid < 16) {  // cur for row tid
        float note = (lgl[tid][0] > 0.0f) ? 1.0f : 0.0f;
        float mx = lgl[tid][1];
        int mi = 0;
        for (int v = 1; v < 32; ++v) {
          float t = lgl[tid][1 + v];
          if (t > mx) { mx = t; mi = v; }
        }
        curs[tid][0] = note;
        curs[tid][1] = (float)mi * (1.0f / 31.0f);
      }
      if (xcc == 0) {  // out write (XCD 0 only; 16*33 = 528 cells)
        for (int q = tid; q < 16 * NOUTC; q += 512) {
          int rl = q / NOUTC, chn = q - rl * NOUTC;
          int r = row0 + rl;
          out[((size_t)((r >> 6) * NOUTC + chn) * 64 + (r & 63)) * 128 + (s - 1)] =
              lgl[rl][chn];
        }
      }
    }
    __syncthreads();
    // layer-0 epilogue (all 512 threads; 1 row x 4 cols each)
    {
      float cu0v = (s == 0) ? sos0 : curs[erow][0];
      float cu1v = (s == 0) ? sos1 : curs[erow][1];
      f4v aI = *(const f4v*)&accst[0][erow][ecb];
      f4v aF = *(const f4v*)&accst[1][erow][ecb];
      f4v aG = *(const f4v*)&accst[2][erow][ecb];
      f4v aO = *(const f4v*)&accst[3][erow][ecb];
      union { u64 pk; short hv[4]; } u;
#pragma unroll
      for (int cc = 0; cc < 4; ++cc) {
        float gi = aI[cc] + c0vv[0][cc] + cu0v * wf0v[0][cc] + cu1v * wf1v[0][cc];
        float gf = aF[cc] + c0vv[1][cc] + cu0v * wf0v[1][cc] + cu1v * wf1v[1][cc];
        float gg = aG[cc] + c0vv[2][cc] + cu0v * wf0v[2][cc] + cu1v * wf1v[2][cc];
        float go = aO[cc] + c0vv[3][cc] + cu0v * wf0v[3][cc] + cu1v * wf1v[3][cc];
        float ccv = fsig(gf) * c0s[cc] + fsig(gi) * ftanh(gg);
        c0s[cc] = ccv;
        u.hv[cc] = f2bf(fsig(go) * ftanh(ccv));
      }
      u64* dst = (u64*)(hbuf + (size_t)gr * G4 + bank_w + x * 128 + ecb);
      sink ^= __hip_atomic_exchange(dst, u.pk, __ATOMIC_RELAXED,
                                    __HIP_MEMORY_SCOPE_SYSTEM);
    }
    ++snum; gridbar(gbar, snum * 256u);

    // ================= Phase B: layer-1 =================
    stage16(Ast, hbuf, row0, bank_w, tid);  // h0_new rows (all cols, all XCDs)
    asm volatile("s_waitcnt vmcnt(0)" ::: "memory");
    __syncthreads();
    {
      f4v acc[4];
#pragma unroll
      for (int j = 0; j < 4; ++j) acc[j] = (f4v){0.f, 0.f, 0.f, 0.f};
#pragma unroll 4
      for (int kk = 0; kk < 32; ++kk) {  // chain 1: h0_new @ Wih1
        s8v av = *(const s8v*)&Ast[l16][quad8 + kk * 32];
#pragma unroll
        for (int j = 0; j < 4; ++j) {
          s8v bv = *(const s8v*)(WT1 + (nb1[j] + kk) * 512 + (size_t)lane * 8);
          acc[j] = __builtin_amdgcn_mfma_f32_16x16x32_bf16(av, bv, acc[j], 0, 0, 0);
        }
      }
      if (s > 0) {
#pragma unroll 4
        for (int kk = 0; kk < 32; ++kk) {  // chain 2: h1_prev @ Whh1
          s8v av = *(const s8v*)&Bst[l16][quad8 + kk * 32];
#pragma unroll
          for (int j = 0; j < 4; ++j) {
            s8v bv = *(const s8v*)(WT1 + (nb1[j] + 32 + kk) * 512 + (size_t)lane * 8);
            acc[j] = __builtin_amdgcn_mfma_f32_16x16x32_bf16(av, bv, acc[j], 0, 0, 0);
          }
        }
      }
#pragma unroll
      for (int j = 0; j < 4; ++j)
#pragma unroll
        for (int p = 0; p < 4; ++p)
          accst[g][quad * 4 + p][(half * 4 + j) * 16 + l16] = acc[j][p];
    }
    __syncthreads();
    // layer-1 epilogue
    {
      f4v aI = *(const f4v*)&accst[0][erow][ecb];
      f4v aF = *(const f4v*)&accst[1][erow][ecb];
      f4v aG = *(const f4v*)&accst[2][erow][ecb];
      f4v aO = *(const f4v*)&accst[3][erow][ecb];
      union { u64 pk; short hv[4]; } u;
#pragma unroll
      for (int cc = 0; cc < 4; ++cc) {
        float gi = aI[cc] + b1vv[0][cc];
        float gf = aF[cc] + b1vv[1][cc];
        float gg = aG[cc] + b1vv[2][cc];
        float go = aO[cc] + b1vv[3][cc];
        float ccv = fsig(gf) * c1s[cc] + fsig(gi) * ftanh(gg);
        c1s[cc] = ccv;
        u.hv[cc] = f2bf(fsig(go) * ftanh(ccv));
      }
      u64* dst = (u64*)(hbuf + (size_t)gr * G4 + bank_w + 1024 + x * 128 + ecb);
      sink ^= __hip_atomic_exchange(dst, u.pk, __ATOMIC_RELAXED,
                                    __HIP_MEMORY_SCOPE_SYSTEM);
    }
    ++snum; gridbar(gbar, snum * 256u);
  }

  // final logits for s=127 (h1(127) sits in bank 0, +1024)
  if (xcc == 0) {
    stage16(Bst, hbuf, row0, 0 + 1024, tid);
    asm volatile("s_waitcnt vmcnt(0)" ::: "memory");
    __syncthreads();
    if (w < 3) {
      f4v la = {0.f, 0.f, 0.f, 0.f};
      const short* bh = WoFh + (size_t)w * 32 * 512 + (size_t)lane * 8;
      const short* bl = WoFl + (size_t)w * 32 * 512 + (size_t)lane * 8;
#pragma unroll 4
      for (int kk = 0; kk < 32; ++kk) {
        s8v av = *(const s8v*)&Bst[l16][quad8 + kk * 32];
        la = __builtin_amdgcn_mfma_f32_16x16x32_bf16(av, *(const s8v*)(bh + (size_t)kk * 512), la, 0, 0, 0);
        la = __builtin_amdgcn_mfma_f32_16x16x32_bf16(av, *(const s8v*)(bl + (size_t)kk * 512), la, 0, 0, 0);
      }
      int r0 = quad * 4;
#pragma unroll
      for (int p = 0; p < 4; ++p) {
        if (w == 0)      lgl[r0 + p][l16]      = la[p] + boA;
        else if (w == 1) lgl[r0 + p][16 + l16] = la[p] + boA;
        else if (l16 == 0) lgl[r0 + p][32]     = la[p] + boA;
      }
    }
    __syncthreads();
    for (int q = tid; q < 16 * NOUTC; q += 512) {
      int rl = q / NOUTC, chn = q - rl * NOUTC;
      int r = row0 + rl;
      out[((size_t)((r >> 6) * NOUTC + chn) * 64 + (r & 63)) * 128 + (NSTEPS - 1)] =
          lgl[rl][chn];
    }
  }
  asm volatile("" :: "v"(sink));  // keep returning-form atomics live
}

// ---------------- host launch -------------------------------------------------
extern "C" void kernel_launch(void* const* d_in, const int* in_sizes, int n_in,
                              void* d_out, int out_size, void* d_ws, size_t ws_size,
                              hipStream_t stream) {
  (void)in_sizes; (void)n_in; (void)out_size; (void)ws_size;
  const float* x    = (const float*)d_in[0];
  const float* sos  = (const float*)d_in[1];
  const float* Wc   = (const float*)d_in[2];
  const float* bc   = (const float*)d_in[3];
  const float* Wi   = (const float*)d_in[4];
  const float* bi   = (const float*)d_in[5];
  const float* Wih0 = (const float*)d_in[6];
  const float* Whh0 = (const float*)d_in[7];
  const float* bih0 = (const float*)d_in[8];
  const float* bhh0 = (const float*)d_in[9];
  const float* Wih1 = (const float*)d_in[10];
  const float* Whh1 = (const float*)d_in[11];
  const float* bih1 = (const float*)d_in[12];
  const float* bhh1 = (const float*)d_in[13];
  const float* Wo   = (const float*)d_in[14];
  const float* bo   = (const float*)d_in[15];
  float* out = (float*)d_out;

  char* p = (char*)d_ws;
  short* WT0    = (short*)p; p += (size_t)256 * 32 * 512 * 2;  // 8 MB
  short* WT1    = (short*)p; p += (size_t)256 * 64 * 512 * 2;  // 16 MB
  short* WTc_hi = (short*)p; p += (size_t)256 * 32 * 512 * 2;  // 8 MB
  short* WTc_lo = (short*)p; p += (size_t)256 * 32 * 512 * 2;  // 8 MB
  float* const0 = (float*)p; p += (size_t)512 * 4096 * 4;      // 8 MB
  short* hbuf   = (short*)p; p += (size_t)512 * 4096 * 2;      // 4 MB
  short* cond_hi= (short*)p; p += (size_t)512 * 1024 * 2;      // 1 MB
  short* cond_lo= (short*)p; p += (size_t)512 * 1024 * 2;      // 1 MB
  float* vec0   = (float*)p; p += 4096 * 4;
  float* Wf     = (float*)p; p += 4096 * 2 * 4;
  float* b1vec  = (float*)p; p += 4096 * 4;
  short* WoFh   = (short*)p; p += (size_t)48 * 1024 * 2;       // 96 KB
  short* WoFl   = (short*)p; p += (size_t)48 * 1024 * 2;       // 96 KB
  u32*   bar    = (u32*)p;   p += 4096;  // [0..7] XCD slot claims; [64] global barrier

  hipMemsetAsync(bar, 0, 4096, stream);

  transpose_frag_kernel<<<1024, 256, 0, stream>>>(Whh0, WT0, nullptr, 32, 0);
  transpose_frag_kernel<<<1024, 256, 0, stream>>>(Wih1, WT1, nullptr, 64, 0);
  transpose_frag_kernel<<<1024, 256, 0, stream>>>(Whh1, WT1, nullptr, 64, 32);
  transpose_frag_kernel<<<1024, 256, 0, stream>>>(Wih0 + (size_t)1024 * 4096,
                                                  WTc_hi, WTc_lo, 32, 0);
  cond_kernel<<<256, 256, 0, stream>>>(x, Wc, bc, cond_hi, cond_lo);
  vecs_kernel<<<16, 256, 0, stream>>>(Wih0, bi, Wi, bih0, bhh0, bih1, bhh1,
                                      vec0, Wf, b1vec);
  wof_kernel<<<96, 64, 0, stream>>>(Wo, WoFh, WoFl);
  const0_kernel<<<256, 512, 0, stream>>>(cond_hi, cond_lo, WTc_hi, WTc_lo,
                                         vec0, const0);
  lstm_main<<<2048, 512, 0, stream>>>(WT0, WT1, const0, Wf, b1vec, WoFh, WoFl,
                                      bo, sos, out, hbuf, bar);
}

// Round 9
// 6546.058 us; speedup vs baseline: 2.7837x; 1.1029x over previous
//
#include <hip/hip_runtime.h>
#include <hip/hip_bf16.h>

// LSTMOutputProj: 2-layer LSTM (H=1024), 128 steps, BT=512 rows.
// COLUMN-PARTITIONED persistent kernel: XCD x owns hidden cols x*128..x*128+127
// (all 4 gates, both layers). Weight slice = 3 MB -> permanently L2-resident.
// 32 blocks/XCD (runtime XCC claim), block jb owns rows jb*16..jb*16+15.
// Cross-XCD h exchange through the MALL:
//   - h writes: RETURNING system-scope atomic exchange (completes AT the MALL;
//     return proves visibility), drained by vmcnt(0) before barrier arrival.
//   - h reads: system-scope bypass loads staged into LDS (conflict-free order).
//   - barrier: PER-JB groups of 8 blocks (one per XCD) -- the dependency graph
//     is row-local, so no global barrier is needed. 8 arrivals, 64B-spaced
//     counters. NO fences ever -> L2 weight residency preserved.
// LDS layouts tuned: stage writes contiguous per wave; accst padded to 132.

#define G4     4096
#define NSTEPS 128
#define NOUTC  33

typedef __attribute__((ext_vector_type(8))) short s8v;
typedef __attribute__((ext_vector_type(4))) float f4v;
typedef unsigned int u32;
typedef unsigned long long u64;

__device__ __forceinline__ float fsig(float x)  { return 1.0f / (1.0f + __expf(-x)); }
__device__ __forceinline__ float ftanh(float x) { return 2.0f / (1.0f + __expf(-2.0f * x)) - 1.0f; }

__device__ __forceinline__ short f2bf(float x) {
  union { __hip_bfloat16 b; short s; } u; u.b = __float2bfloat16(x); return u.s;
}
__device__ __forceinline__ float bf2f(short s) {
  union { __hip_bfloat16 b; short v; } u; u.v = s; return __bfloat162float(u.b);
}

// ---------------- per-group barrier (8 arrivals, no cache maintenance) --------
__device__ __forceinline__ void gridbar(u32* bar, u32 target) {
  asm volatile("s_waitcnt vmcnt(0)" ::: "memory");  // drain swaps (returns back)
  __syncthreads();
  if (threadIdx.x == 0) {
    __hip_atomic_fetch_add(bar, 1u, __ATOMIC_RELAXED, __HIP_MEMORY_SCOPE_SYSTEM);
    while (__hip_atomic_load(bar, __ATOMIC_RELAXED, __HIP_MEMORY_SCOPE_SYSTEM) < target) {
      __builtin_amdgcn_s_sleep(1);
    }
  }
  __syncthreads();
}

// ---------------- stage 16 rows x 1024 bf16 of h from MALL into LDS -----------
// q = i*512 + tid: per-wave LDS writes are 512 contiguous bytes -> conflict-free;
// global reads are fully coalesced (64 consecutive u64 per wave).
__device__ __forceinline__ void stage16(short (*dst)[1032], const short* hbuf,
                                        int row0, int bankoff, int tid) {
#pragma unroll
  for (int i = 0; i < 8; ++i) {
    int q = i * 512 + tid;        // 0..4095 u64 chunks (16 rows x 256)
    int row = q >> 8, c4 = q & 255;
    const u64* src = (const u64*)(hbuf + (size_t)(row0 + row) * G4 + bankoff) + c4;
    u64 v = __hip_atomic_load(src, __ATOMIC_RELAXED, __HIP_MEMORY_SCOPE_SYSTEM);
    *(u64*)&dst[row][c4 * 4] = v;
  }
}

// ---------------- precompute: transpose -> fragment-linearized bf16 -----------
__global__ __launch_bounds__(256) void transpose_frag_kernel(
    const float* __restrict__ src, short* __restrict__ dst_hi,
    short* __restrict__ dst_lo, int NK, int koff) {
  __shared__ float St[64][65];
  int n0 = (blockIdx.x & 63) * 64;
  int k0 = (blockIdx.x >> 6) * 64;
  int t = threadIdx.x;
  int nl = t & 63, kl = t >> 6;
#pragma unroll
  for (int it = 0; it < 16; ++it) {
    int k = kl + it * 4;
    St[k][nl] = src[(size_t)(k0 + k) * 4096 + n0 + nl];
  }
  __syncthreads();
  int lane = t & 63, w = t >> 6;
  for (int it = 0; it < 2; ++it) {
    int sub = it * 4 + w;  // 0..7 : 4 ntiles x 2 kchunks
    int nt = sub >> 1, kc = sub & 1;
    int nloc = nt * 16 + (lane & 15);
    int kbase = kc * 32 + (lane >> 4) * 8;
    float v[8];
#pragma unroll
    for (int ii = 0; ii < 8; ++ii) v[ii] = St[kbase + ii][nloc];
    s8v hv;
#pragma unroll
    for (int ii = 0; ii < 8; ++ii) hv[ii] = f2bf(v[ii]);
    size_t ntg = (size_t)(n0 / 16 + nt);
    size_t kcg = (size_t)(k0 / 32 + kc + koff);
    size_t off = (ntg * (size_t)NK + kcg) * 512 + (size_t)lane * 8;
    *(s8v*)(dst_hi + off) = hv;
    if (dst_lo) {
      s8v lv;
#pragma unroll
      for (int ii = 0; ii < 8; ++ii) lv[ii] = f2bf(v[ii] - bf2f(hv[ii]));
      *(s8v*)(dst_lo + off) = lv;
    }
  }
}

// ---------------- precompute: cond = x @ Wc + bc  (fp32, split to bf16 hi/lo) -
__global__ __launch_bounds__(256) void cond_kernel(
    const float* __restrict__ x, const float* __restrict__ Wc,
    const float* __restrict__ bc, short* __restrict__ cond_hi,
    short* __restrict__ cond_lo) {
  __shared__ float xs[8][512];
  int rb = (blockIdx.x >> 2) * 8;
  int cb = (blockIdx.x & 3) * 256;
  int t = threadIdx.x;
  for (int i = t; i < 8 * 512; i += 256)
    xs[i >> 9][i & 511] = x[(size_t)(rb + (i >> 9)) * 512 + (i & 511)];
  __syncthreads();
  float acc[8] = {0, 0, 0, 0, 0, 0, 0, 0};
  for (int k = 0; k < 512; ++k) {
    float w = Wc[(size_t)k * 1024 + cb + t];
#pragma unroll
    for (int rr = 0; rr < 8; ++rr) acc[rr] += xs[rr][k] * w;
  }
  float bcv = bc[cb + t];
#pragma unroll
  for (int rr = 0; rr < 8; ++rr) {
    float v = acc[rr] + bcv;
    short hi = f2bf(v);
    cond_hi[(size_t)(rb + rr) * 1024 + cb + t] = hi;
    cond_lo[(size_t)(rb + rr) * 1024 + cb + t] = f2bf(v - bf2f(hi));
  }
}

// ---------------- precompute: vec0, Wf, b1vec ---------------------------------
__global__ __launch_bounds__(256) void vecs_kernel(
    const float* __restrict__ Wih0, const float* __restrict__ bi,
    const float* __restrict__ Wi, const float* __restrict__ bih0,
    const float* __restrict__ bhh0, const float* __restrict__ bih1,
    const float* __restrict__ bhh1, float* __restrict__ vec0,
    float* __restrict__ Wf, float* __restrict__ b1vec) {
  int n = blockIdx.x * 256 + threadIdx.x;  // 0..4095
  float v0 = 0.f, w0 = 0.f, w1 = 0.f;
  for (int k = 0; k < 1024; ++k) {
    float w = Wih0[(size_t)k * 4096 + n];
    v0 += bi[k] * w;
    w0 += Wi[k] * w;
    w1 += Wi[1024 + k] * w;
  }
  vec0[n] = v0 + bih0[n] + bhh0[n];
  Wf[2 * n + 0] = w0;
  Wf[2 * n + 1] = w1;
  b1vec[n] = bih1[n] + bhh1[n];
}

// ---------------- precompute: Wo -> fragment-linearized bf16 hi/lo, N=48 pad --
__global__ __launch_bounds__(64) void wof_kernel(const float* __restrict__ Wo,
                                                 short* __restrict__ hi,
                                                 short* __restrict__ lo) {
  int nt = blockIdx.x >> 5;   // 0..2
  int kc = blockIdx.x & 31;   // 0..31
  int lane = threadIdx.x;     // 0..63
  int ch = nt * 16 + (lane & 15);
  int kb = kc * 32 + (lane >> 4) * 8;
  s8v hv, lv;
#pragma unroll
  for (int ii = 0; ii < 8; ++ii) {
    float v = (ch < NOUTC) ? Wo[(size_t)(kb + ii) * NOUTC + ch] : 0.f;
    short h = f2bf(v);
    hv[ii] = h;
    lv[ii] = f2bf(v - bf2f(h));
  }
  size_t off = ((size_t)(nt * 32 + kc)) * 512 + (size_t)lane * 8;
  *(s8v*)(hi + off) = hv;
  *(s8v*)(lo + off) = lv;
}

// ---------------- precompute: const0 = cond @ Wih0[H:] + vec0  (split bf16) ---
__global__ __launch_bounds__(512) void const0_kernel(
    const short* __restrict__ cond_hi, const short* __restrict__ cond_lo,
    const short* __restrict__ WTc_hi, const short* __restrict__ WTc_lo,
    const float* __restrict__ vec0, float* __restrict__ const0) {
  int j = blockIdx.x & 63, i = blockIdx.x >> 6;
  int w = threadIdx.x >> 6, lane = threadIdx.x & 63;
  int quad = lane >> 4, l16 = lane & 15;
  int rowA = i * 128 + w * 16 + l16;
  int rowC = i * 128 + w * 16 + quad * 4;
  int hid = j * 16 + l16;
  const short* ah = cond_hi + (size_t)rowA * 1024 + quad * 8;
  const short* al = cond_lo + (size_t)rowA * 1024 + quad * 8;
  f4v acc[4];
#pragma unroll
  for (int g = 0; g < 4; ++g) acc[g] = (f4v){0.f, 0.f, 0.f, 0.f};
#pragma unroll 2
  for (int kk = 0; kk < 32; ++kk) {
    s8v avh = *(const s8v*)(ah + kk * 32);
    s8v avl = *(const s8v*)(al + kk * 32);
#pragma unroll
    for (int g = 0; g < 4; ++g) {
      size_t off = ((size_t)(g * 64 + j) * 32 + kk) * 512 + (size_t)lane * 8;
      s8v bh = *(const s8v*)(WTc_hi + off);
      s8v bl = *(const s8v*)(WTc_lo + off);
      acc[g] = __builtin_amdgcn_mfma_f32_16x16x32_bf16(avh, bh, acc[g], 0, 0, 0);
      acc[g] = __builtin_amdgcn_mfma_f32_16x16x32_bf16(avh, bl, acc[g], 0, 0, 0);
      acc[g] = __builtin_amdgcn_mfma_f32_16x16x32_bf16(avl, bh, acc[g], 0, 0, 0);
    }
  }
#pragma unroll
  for (int g = 0; g < 4; ++g) {
    float vv = vec0[g * 1024 + hid];
#pragma unroll
    for (int p = 0; p < 4; ++p) {
      int r = rowC + p;
      const0[(size_t)r * G4 + g * 1024 + hid] = acc[g][p] + vv;
    }
  }
}

// ---------------- main persistent kernel --------------------------------------
__global__ __launch_bounds__(512) void lstm_main(
    const short* __restrict__ WT0, const short* __restrict__ WT1,
    const float* __restrict__ const0, const float* __restrict__ Wf,
    const float* __restrict__ b1vec, const short* __restrict__ WoFh,
    const short* __restrict__ WoFl, const float* __restrict__ bo,
    const float* __restrict__ sos, float* __restrict__ out,
    short* __restrict__ hbuf, u32* __restrict__ bar) {
  int tid = threadIdx.x;
  u32 xcc;
  asm volatile("s_getreg_b32 %0, hwreg(20, 0, 32)" : "=s"(xcc));
  xcc &= 7;
  __shared__ u32 sslot;
  if (tid == 0)
    sslot = __hip_atomic_fetch_add(&bar[xcc], 1u, __ATOMIC_RELAXED,
                                   __HIP_MEMORY_SCOPE_SYSTEM);
  __syncthreads();
  u32 jb = sslot;
  if (jb >= 32) return;          // surplus block on a full XCD
  u32* gbar = bar + 64 + (size_t)jb * 16;  // per-jb group counter (8 arrivals)

  int w = tid >> 6, lane = tid & 63;
  int g = w >> 1, half = w & 1;  // wave -> gate g, ntile-half
  int quad = lane >> 4, l16 = lane & 15;
  int quad8 = quad * 8;
  int x = (int)xcc;
  int row0 = (int)jb * 16;       // block's 16 rows (same rows on every XCD)
  int erow = tid >> 5;           // epilogue: row within block (0..15)
  int ecb  = (tid & 31) * 4;     // epilogue: col base within slice (0..124)
  int gr = row0 + erow;          // global row of epilogue cells

  __shared__ short Ast[16][1032];   // staged A (h0_prev / h0_new), +8 pad
  __shared__ short Bst[16][1032];   // staged h1_prev
  __shared__ float accst[4][16][132];  // gate partials, padded stride (bank-safe)
  __shared__ float lgl[16][34];
  __shared__ float curs[16][2];

  // step-invariant per-thread constants (epilogue cells: 1 row x 4 cols)
  float wf0v[4][4], wf1v[4][4], b1vv[4][4], c0vv[4][4];
#pragma unroll
  for (int g2 = 0; g2 < 4; ++g2)
#pragma unroll
    for (int cc = 0; cc < 4; ++cc) {
      int n = g2 * 1024 + x * 128 + ecb + cc;
      wf0v[g2][cc] = Wf[2 * n + 0];
      wf1v[g2][cc] = Wf[2 * n + 1];
      b1vv[g2][cc] = b1vec[n];
      c0vv[g2][cc] = const0[(size_t)gr * G4 + n];
    }
  size_t nb0[4], nb1[4];
#pragma unroll
  for (int j = 0; j < 4; ++j) {
    int nt = g * 64 + x * 8 + half * 4 + j;  // global ntile of this wave's j-th tile
    nb0[j] = (size_t)nt * 32;
    nb1[j] = (size_t)nt * 64;
  }
  float boA = (w == 0) ? bo[l16] : ((w == 1) ? bo[16 + l16] : bo[32]);
  float sos0 = sos[0], sos1 = sos[1];
  float c0s[4] = {0.f, 0.f, 0.f, 0.f};
  float c1s[4] = {0.f, 0.f, 0.f, 0.f};
  u64 sink = 0;
  u32 snum = 0;

  for (int s = 0; s < NSTEPS; ++s) {
    int bank_r = (s & 1) * 2048;
    int bank_w = ((s + 1) & 1) * 2048;

    // ================= Phase A: logits+cur (s-1) and layer-0 =================
    if (s > 0) {
      stage16(Ast, hbuf, row0, bank_r, tid);         // h0_prev rows
      stage16(Bst, hbuf, row0, bank_r + 1024, tid);  // h1_prev rows
      asm volatile("s_waitcnt vmcnt(0)" ::: "memory");
      __syncthreads();
      if (w < 3) {  // logits: 3 waves, one Wo ntile each (hi/lo interleave)
        f4v la = {0.f, 0.f, 0.f, 0.f};
        const short* bh = WoFh + (size_t)w * 32 * 512 + (size_t)lane * 8;
        const short* bl = WoFl + (size_t)w * 32 * 512 + (size_t)lane * 8;
#pragma unroll 4
        for (int kk = 0; kk < 32; ++kk) {
          s8v av = *(const s8v*)&Bst[l16][quad8 + kk * 32];
          la = __builtin_amdgcn_mfma_f32_16x16x32_bf16(av, *(const s8v*)(bh + (size_t)kk * 512), la, 0, 0, 0);
          la = __builtin_amdgcn_mfma_f32_16x16x32_bf16(av, *(const s8v*)(bl + (size_t)kk * 512), la, 0, 0, 0);
        }
        int r0 = quad * 4;
#pragma unroll
        for (int p = 0; p < 4; ++p) {
          if (w == 0)      lgl[r0 + p][l16]      = la[p] + boA;
          else if (w == 1) lgl[r0 + p][16 + l16] = la[p] + boA;
          else if (l16 == 0) lgl[r0 + p][32]     = la[p] + boA;
        }
      }
    }
    // layer-0 gemm: g0 = h0_prev @ Whh0 (K=1024) for this wave's 4 ntiles
    {
      f4v acc[4];
#pragma unroll
      for (int j = 0; j < 4; ++j) acc[j] = (f4v){0.f, 0.f, 0.f, 0.f};
      if (s > 0) {
#pragma unroll 4
        for (int kk = 0; kk < 32; ++kk) {
          s8v av = *(const s8v*)&Ast[l16][quad8 + kk * 32];
#pragma unroll
          for (int j = 0; j < 4; ++j) {
            s8v bv = *(const s8v*)(WT0 + (nb0[j] + kk) * 512 + (size_t)lane * 8);
            acc[j] = __builtin_amdgcn_mfma_f32_16x16x32_bf16(av, bv, acc[j], 0, 0, 0);
          }
        }
      }
#pragma unroll
      for (int j = 0; j < 4; ++j)
#pragma unroll
        for (int p = 0; p < 4; ++p)
          accst[g][quad * 4 + p][(half * 4 + j) * 16 + l16] = acc[j][p];
    }
    __syncthreads();
    if (s > 0) {
      if (tid < 16) {  // cur for row tid
        float note = (lgl[tid][0] > 0.0f) ? 1.0f : 0.0f;
        float mx = lgl[tid][1];
        int mi = 0;
        for (int v = 1; v < 32; ++v) {
          float t = lgl[tid][1 + v];
          if (t > mx) { mx = t; mi = v; }
        }
        curs[tid][0] = note;
        curs[tid][1] = (float)mi * (1.0f / 31.0f);
      }
      if (xcc == 0) {  // out write (XCD 0 only; 16*33 = 528 cells)
        for (int q = tid; q < 16 * NOUTC; q += 512) {
          int rl = q / NOUTC, chn = q - rl * NOUTC;
          int r = row0 + rl;
          out[((size_t)((r >> 6) * NOUTC + chn) * 64 + (r & 63)) * 128 + (s - 1)] =
              lgl[rl][chn];
        }
      }
    }
    __syncthreads();
    // layer-0 epilogue (all 512 threads; 1 row x 4 cols each)
    {
      float cu0v = (s == 0) ? sos0 : curs[erow][0];
      float cu1v = (s == 0) ? sos1 : curs[erow][1];
      f4v aI = *(const f4v*)&accst[0][erow][ecb];
      f4v aF = *(const f4v*)&accst[1][erow][ecb];
      f4v aG = *(const f4v*)&accst[2][erow][ecb];
      f4v aO = *(const f4v*)&accst[3][erow][ecb];
      union { u64 pk; short hv[4]; } u;
#pragma unroll
      for (int cc = 0; cc < 4; ++cc) {
        float gi = aI[cc] + c0vv[0][cc] + cu0v * wf0v[0][cc] + cu1v * wf1v[0][cc];
        float gf = aF[cc] + c0vv[1][cc] + cu0v * wf0v[1][cc] + cu1v * wf1v[1][cc];
        float gg = aG[cc] + c0vv[2][cc] + cu0v * wf0v[2][cc] + cu1v * wf1v[2][cc];
        float go = aO[cc] + c0vv[3][cc] + cu0v * wf0v[3][cc] + cu1v * wf1v[3][cc];
        float ccv = fsig(gf) * c0s[cc] + fsig(gi) * ftanh(gg);
        c0s[cc] = ccv;
        u.hv[cc] = f2bf(fsig(go) * ftanh(ccv));
      }
      u64* dst = (u64*)(hbuf + (size_t)gr * G4 + bank_w + x * 128 + ecb);
      sink ^= __hip_atomic_exchange(dst, u.pk, __ATOMIC_RELAXED,
                                    __HIP_MEMORY_SCOPE_SYSTEM);
    }
    ++snum; gridbar(gbar, snum * 8u);

    // ================= Phase B: layer-1 =================
    stage16(Ast, hbuf, row0, bank_w, tid);  // h0_new rows (all cols, all XCDs)
    asm volatile("s_waitcnt vmcnt(0)" ::: "memory");
    __syncthreads();
    {
      f4v acc[4];
#pragma unroll
      for (int j = 0; j < 4; ++j) acc[j] = (f4v){0.f, 0.f, 0.f, 0.f};
#pragma unroll 4
      for (int kk = 0; kk < 32; ++kk) {  // chain 1: h0_new @ Wih1
        s8v av = *(const s8v*)&Ast[l16][quad8 + kk * 32];
#pragma unroll
        for (int j = 0; j < 4; ++j) {
          s8v bv = *(const s8v*)(WT1 + (nb1[j] + kk) * 512 + (size_t)lane * 8);
          acc[j] = __builtin_amdgcn_mfma_f32_16x16x32_bf16(av, bv, acc[j], 0, 0, 0);
        }
      }
      if (s > 0) {
#pragma unroll 4
        for (int kk = 0; kk < 32; ++kk) {  // chain 2: h1_prev @ Whh1
          s8v av = *(const s8v*)&Bst[l16][quad8 + kk * 32];
#pragma unroll
          for (int j = 0; j < 4; ++j) {
            s8v bv = *(const s8v*)(WT1 + (nb1[j] + 32 + kk) * 512 + (size_t)lane * 8);
            acc[j] = __builtin_amdgcn_mfma_f32_16x16x32_bf16(av, bv, acc[j], 0, 0, 0);
          }
        }
      }
#pragma unroll
      for (int j = 0; j < 4; ++j)
#pragma unroll
        for (int p = 0; p < 4; ++p)
          accst[g][quad * 4 + p][(half * 4 + j) * 16 + l16] = acc[j][p];
    }
    __syncthreads();
    // layer-1 epilogue
    {
      f4v aI = *(const f4v*)&accst[0][erow][ecb];
      f4v aF = *(const f4v*)&accst[1][erow][ecb];
      f4v aG = *(const f4v*)&accst[2][erow][ecb];
      f4v aO = *(const f4v*)&accst[3][erow][ecb];
      union { u64 pk; short hv[4]; } u;
#pragma unroll
      for (int cc = 0; cc < 4; ++cc) {
        float gi = aI[cc] + b1vv[0][cc];
        float gf = aF[cc] + b1vv[1][cc];
        float gg = aG[cc] + b1vv[2][cc];
        float go = aO[cc] + b1vv[3][cc];
        float ccv = fsig(gf) * c1s[cc] + fsig(gi) * ftanh(gg);
        c1s[cc] = ccv;
        u.hv[cc] = f2bf(fsig(go) * ftanh(ccv));
      }
      u64* dst = (u64*)(hbuf + (size_t)gr * G4 + bank_w + 1024 + x * 128 + ecb);
      sink ^= __hip_atomic_exchange(dst, u.pk, __ATOMIC_RELAXED,
                                    __HIP_MEMORY_SCOPE_SYSTEM);
    }
    ++snum; gridbar(gbar, snum * 8u);
  }

  // final logits for s=127 (h1(127) sits in bank 0, +1024)
  if (xcc == 0) {
    stage16(Bst, hbuf, row0, 0 + 1024, tid);
    asm volatile("s_waitcnt vmcnt(0)" ::: "memory");
    __syncthreads();
    if (w < 3) {
      f4v la = {0.f, 0.f, 0.f, 0.f};
      const short* bh = WoFh + (size_t)w * 32 * 512 + (size_t)lane * 8;
      const short* bl = WoFl + (size_t)w * 32 * 512 + (size_t)lane * 8;
#pragma unroll 4
      for (int kk = 0; kk < 32; ++kk) {
        s8v av = *(const s8v*)&Bst[l16][quad8 + kk * 32];
        la = __builtin_amdgcn_mfma_f32_16x16x32_bf16(av, *(const s8v*)(bh + (size_t)kk * 512), la, 0, 0, 0);
        la = __builtin_amdgcn_mfma_f32_16x16x32_bf16(av, *(const s8v*)(bl + (size_t)kk * 512), la, 0, 0, 0);
      }
      int r0 = quad * 4;
#pragma unroll
      for (int p = 0; p < 4; ++p) {
        if (w == 0)      lgl[r0 + p][l16]      = la[p] + boA;
        else if (w == 1) lgl[r0 + p][16 + l16] = la[p] + boA;
        else if (l16 == 0) lgl[r0 + p][32]     = la[p] + boA;
      }
    }
    __syncthreads();
    for (int q = tid; q < 16 * NOUTC; q += 512) {
      int rl = q / NOUTC, chn = q - rl * NOUTC;
      int r = row0 + rl;
      out[((size_t)((r >> 6) * NOUTC + chn) * 64 + (r & 63)) * 128 + (NSTEPS - 1)] =
          lgl[rl][chn];
    }
  }
  asm volatile("" :: "v"(sink));  // keep returning-form atomics live
}

// ---------------- host launch -------------------------------------------------
extern "C" void kernel_launch(void* const* d_in, const int* in_sizes, int n_in,
                              void* d_out, int out_size, void* d_ws, size_t ws_size,
                              hipStream_t stream) {
  (void)in_sizes; (void)n_in; (void)out_size; (void)ws_size;
  const float* x    = (const float*)d_in[0];
  const float* sos  = (const float*)d_in[1];
  const float* Wc   = (const float*)d_in[2];
  const float* bc   = (const float*)d_in[3];
  const float* Wi   = (const float*)d_in[4];
  const float* bi   = (const float*)d_in[5];
  const float* Wih0 = (const float*)d_in[6];
  const float* Whh0 = (const float*)d_in[7];
  const float* bih0 = (const float*)d_in[8];
  const float* bhh0 = (const float*)d_in[9];
  const float* Wih1 = (const float*)d_in[10];
  const float* Whh1 = (const float*)d_in[11];
  const float* bih1 = (const float*)d_in[12];
  const float* bhh1 = (const float*)d_in[13];
  const float* Wo   = (const float*)d_in[14];
  const float* bo   = (const float*)d_in[15];
  float* out = (float*)d_out;

  char* p = (char*)d_ws;
  short* WT0    = (short*)p; p += (size_t)256 * 32 * 512 * 2;  // 8 MB
  short* WT1    = (short*)p; p += (size_t)256 * 64 * 512 * 2;  // 16 MB
  short* WTc_hi = (short*)p; p += (size_t)256 * 32 * 512 * 2;  // 8 MB
  short* WTc_lo = (short*)p; p += (size_t)256 * 32 * 512 * 2;  // 8 MB
  float* const0 = (float*)p; p += (size_t)512 * 4096 * 4;      // 8 MB
  short* hbuf   = (short*)p; p += (size_t)512 * 4096 * 2;      // 4 MB
  short* cond_hi= (short*)p; p += (size_t)512 * 1024 * 2;      // 1 MB
  short* cond_lo= (short*)p; p += (size_t)512 * 1024 * 2;      // 1 MB
  float* vec0   = (float*)p; p += 4096 * 4;
  float* Wf     = (float*)p; p += 4096 * 2 * 4;
  float* b1vec  = (float*)p; p += 4096 * 4;
  short* WoFh   = (short*)p; p += (size_t)48 * 1024 * 2;       // 96 KB
  short* WoFl   = (short*)p; p += (size_t)48 * 1024 * 2;       // 96 KB
  u32*   bar    = (u32*)p;   p += 4096;  // [0..7] XCD claims; [64+jb*16] group bars

  hipMemsetAsync(bar, 0, 4096, stream);

  transpose_frag_kernel<<<1024, 256, 0, stream>>>(Whh0, WT0, nullptr, 32, 0);
  transpose_frag_kernel<<<1024, 256, 0, stream>>>(Wih1, WT1, nullptr, 64, 0);
  transpose_frag_kernel<<<1024, 256, 0, stream>>>(Whh1, WT1, nullptr, 64, 32);
  transpose_frag_kernel<<<1024, 256, 0, stream>>>(Wih0 + (size_t)1024 * 4096,
                                                  WTc_hi, WTc_lo, 32, 0);
  cond_kernel<<<256, 256, 0, stream>>>(x, Wc, bc, cond_hi, cond_lo);
  vecs_kernel<<<16, 256, 0, stream>>>(Wih0, bi, Wi, bih0, bhh0, bih1, bhh1,
                                      vec0, Wf, b1vec);
  wof_kernel<<<96, 64, 0, stream>>>(Wo, WoFh, WoFl);
  const0_kernel<<<256, 512, 0, stream>>>(cond_hi, cond_lo, WTc_hi, WTc_lo,
                                         vec0, const0);
  lstm_main<<<2048, 512, 0, stream>>>(WT0, WT1, const0, Wf, b1vec, WoFh, WoFl,
                                      bo, sos, out, hbuf, bar);
}

// Round 11
// 6188.276 us; speedup vs baseline: 2.9446x; 1.0578x over previous
//
#include <hip/hip_runtime.h>
#include <hip/hip_bf16.h>

// LSTMOutputProj: 2-layer LSTM (H=1024), 128 steps, BT=512 rows.
// COLUMN-PARTITIONED persistent kernel: XCD x owns hidden cols x*128..x*128+127
// (all 4 gates, both layers). Weight slice = 3 MB -> permanently L2-resident.
// 32 blocks/XCD (runtime XCC claim), block jb owns rows jb*16..jb*16+15.
// Cross-XCD h exchange through the MALL:
//   - h writes: RETURNING system-scope atomic exchange (completes AT the MALL),
//     drained by vmcnt(0) before barrier arrival.
//   - h reads: 16B global_load_dwordx4 sc0 sc1 (bypass L1/L2, read MALL),
//     staged into LDS in conflict-free order.
//   - barrier: PER-JB groups of 8 blocks (one per XCD); 8 arrivals.
// Traffic optimizations vs R9:
//   - phase A does NOT re-stage Ast: phase B of step s-1 staged h0 from
//     bank_w(s-1) == bank_r(s) -- same data, still resident in LDS. 24->16MB/step.
//   - phase A issues the Bst stage loads BEFORE the layer-0 gemm (independent
//     accumulators; no accumulation-order change) -> fetch hides under MFMAs.
//   - sched_barrier(0) after each deferred vmcnt(0) (rule-#18 hygiene: stop
//     hipcc hoisting consumers of pending asm-output registers above the wait).
// NO fences ever -> L2 weight residency preserved. Math bit-identical to R4.

#define G4     4096
#define NSTEPS 128
#define NOUTC  33

typedef __attribute__((ext_vector_type(8))) short s8v;
typedef __attribute__((ext_vector_type(4))) float f4v;
typedef unsigned int u32;
typedef unsigned long long u64;

__device__ __forceinline__ float fsig(float x)  { return 1.0f / (1.0f + __expf(-x)); }
__device__ __forceinline__ float ftanh(float x) { return 2.0f / (1.0f + __expf(-2.0f * x)) - 1.0f; }

__device__ __forceinline__ short f2bf(float x) {
  union { __hip_bfloat16 b; short s; } u; u.b = __float2bfloat16(x); return u.s;
}
__device__ __forceinline__ float bf2f(short s) {
  union { __hip_bfloat16 b; short v; } u; u.v = s; return __bfloat162float(u.b);
}

// ---------------- per-group barrier (8 arrivals, no cache maintenance) --------
__device__ __forceinline__ void gridbar(u32* bar, u32 target) {
  asm volatile("s_waitcnt vmcnt(0)" ::: "memory");  // drain swaps (returns back)
  __syncthreads();
  if (threadIdx.x == 0) {
    __hip_atomic_fetch_add(bar, 1u, __ATOMIC_RELAXED, __HIP_MEMORY_SCOPE_SYSTEM);
    while (__hip_atomic_load(bar, __ATOMIC_RELAXED, __HIP_MEMORY_SCOPE_SYSTEM) < target) {
      __builtin_amdgcn_s_sleep(1);
    }
  }
  __syncthreads();
}

// ---------------- staged h fetch: issue 4x16B system-bypass loads -------------
// q = i*512 + tid: per-wave global reads 1KB contiguous (coalesced); LDS writes
// 1KB contiguous (conflict-free). "=&v": outputs never alias addr (R6 lesson).
__device__ __forceinline__ void stage_issue(const short* hbuf, int row0,
                                            int bankoff, int tid, s8v* r) {
#pragma unroll
  for (int i = 0; i < 4; ++i) {
    int q = i * 512 + tid;        // 16B chunk 0..2047 (16 rows x 128)
    int row = q >> 7, c16 = q & 127;
    const short* src = hbuf + (size_t)(row0 + row) * G4 + bankoff + c16 * 8;
    asm volatile("global_load_dwordx4 %0, %1, off sc0 sc1"
                 : "=&v"(r[i]) : "v"(src) : "memory");
  }
}
__device__ __forceinline__ void stage_write(short (*dst)[1032], int tid,
                                            const s8v* r) {
#pragma unroll
  for (int i = 0; i < 4; ++i) {
    int q = i * 512 + tid;
    int row = q >> 7, c16 = q & 127;
    *(s8v*)&dst[row][c16 * 8] = r[i];
  }
}

// ---------------- precompute: transpose -> fragment-linearized bf16 -----------
__global__ __launch_bounds__(256) void transpose_frag_kernel(
    const float* __restrict__ src, short* __restrict__ dst_hi,
    short* __restrict__ dst_lo, int NK, int koff) {
  __shared__ float St[64][65];
  int n0 = (blockIdx.x & 63) * 64;
  int k0 = (blockIdx.x >> 6) * 64;
  int t = threadIdx.x;
  int nl = t & 63, kl = t >> 6;
#pragma unroll
  for (int it = 0; it < 16; ++it) {
    int k = kl + it * 4;
    St[k][nl] = src[(size_t)(k0 + k) * 4096 + n0 + nl];
  }
  __syncthreads();
  int lane = t & 63, w = t >> 6;
  for (int it = 0; it < 2; ++it) {
    int sub = it * 4 + w;  // 0..7 : 4 ntiles x 2 kchunks
    int nt = sub >> 1, kc = sub & 1;
    int nloc = nt * 16 + (lane & 15);
    int kbase = kc * 32 + (lane >> 4) * 8;
    float v[8];
#pragma unroll
    for (int ii = 0; ii < 8; ++ii) v[ii] = St[kbase + ii][nloc];
    s8v hv;
#pragma unroll
    for (int ii = 0; ii < 8; ++ii) hv[ii] = f2bf(v[ii]);
    size_t ntg = (size_t)(n0 / 16 + nt);
    size_t kcg = (size_t)(k0 / 32 + kc + koff);
    size_t off = (ntg * (size_t)NK + kcg) * 512 + (size_t)lane * 8;
    *(s8v*)(dst_hi + off) = hv;
    if (dst_lo) {
      s8v lv;
#pragma unroll
      for (int ii = 0; ii < 8; ++ii) lv[ii] = f2bf(v[ii] - bf2f(hv[ii]));
      *(s8v*)(dst_lo + off) = lv;
    }
  }
}

// ---------------- precompute: cond = x @ Wc + bc  (fp32, split to bf16 hi/lo) -
__global__ __launch_bounds__(256) void cond_kernel(
    const float* __restrict__ x, const float* __restrict__ Wc,
    const float* __restrict__ bc, short* __restrict__ cond_hi,
    short* __restrict__ cond_lo) {
  __shared__ float xs[8][512];
  int rb = (blockIdx.x >> 2) * 8;
  int cb = (blockIdx.x & 3) * 256;
  int t = threadIdx.x;
  for (int i = t; i < 8 * 512; i += 256)
    xs[i >> 9][i & 511] = x[(size_t)(rb + (i >> 9)) * 512 + (i & 511)];
  __syncthreads();
  float acc[8] = {0, 0, 0, 0, 0, 0, 0, 0};
  for (int k = 0; k < 512; ++k) {
    float w = Wc[(size_t)k * 1024 + cb + t];
#pragma unroll
    for (int rr = 0; rr < 8; ++rr) acc[rr] += xs[rr][k] * w;
  }
  float bcv = bc[cb + t];
#pragma unroll
  for (int rr = 0; rr < 8; ++rr) {
    float v = acc[rr] + bcv;
    short hi = f2bf(v);
    cond_hi[(size_t)(rb + rr) * 1024 + cb + t] = hi;
    cond_lo[(size_t)(rb + rr) * 1024 + cb + t] = f2bf(v - bf2f(hi));
  }
}

// ---------------- precompute: vec0, Wf, b1vec ---------------------------------
__global__ __launch_bounds__(256) void vecs_kernel(
    const float* __restrict__ Wih0, const float* __restrict__ bi,
    const float* __restrict__ Wi, const float* __restrict__ bih0,
    const float* __restrict__ bhh0, const float* __restrict__ bih1,
    const float* __restrict__ bhh1, float* __restrict__ vec0,
    float* __restrict__ Wf, float* __restrict__ b1vec) {
  int n = blockIdx.x * 256 + threadIdx.x;  // 0..4095
  float v0 = 0.f, w0 = 0.f, w1 = 0.f;
  for (int k = 0; k < 1024; ++k) {
    float w = Wih0[(size_t)k * 4096 + n];
    v0 += bi[k] * w;
    w0 += Wi[k] * w;
    w1 += Wi[1024 + k] * w;
  }
  vec0[n] = v0 + bih0[n] + bhh0[n];
  Wf[2 * n + 0] = w0;
  Wf[2 * n + 1] = w1;
  b1vec[n] = bih1[n] + bhh1[n];
}

// ---------------- precompute: Wo -> fragment-linearized bf16 hi/lo, N=48 pad --
__global__ __launch_bounds__(64) void wof_kernel(const float* __restrict__ Wo,
                                                 short* __restrict__ hi,
                                                 short* __restrict__ lo) {
  int nt = blockIdx.x >> 5;   // 0..2
  int kc = blockIdx.x & 31;   // 0..31
  int lane = threadIdx.x;     // 0..63
  int ch = nt * 16 + (lane & 15);
  int kb = kc * 32 + (lane >> 4) * 8;
  s8v hv, lv;
#pragma unroll
  for (int ii = 0; ii < 8; ++ii) {
    float v = (ch < NOUTC) ? Wo[(size_t)(kb + ii) * NOUTC + ch] : 0.f;
    short h = f2bf(v);
    hv[ii] = h;
    lv[ii] = f2bf(v - bf2f(h));
  }
  size_t off = ((size_t)(nt * 32 + kc)) * 512 + (size_t)lane * 8;
  *(s8v*)(hi + off) = hv;
  *(s8v*)(lo + off) = lv;
}

// ---------------- precompute: const0 = cond @ Wih0[H:] + vec0  (split bf16) ---
__global__ __launch_bounds__(512) void const0_kernel(
    const short* __restrict__ cond_hi, const short* __restrict__ cond_lo,
    const short* __restrict__ WTc_hi, const short* __restrict__ WTc_lo,
    const float* __restrict__ vec0, float* __restrict__ const0) {
  int j = blockIdx.x & 63, i = blockIdx.x >> 6;
  int w = threadIdx.x >> 6, lane = threadIdx.x & 63;
  int quad = lane >> 4, l16 = lane & 15;
  int rowA = i * 128 + w * 16 + l16;
  int rowC = i * 128 + w * 16 + quad * 4;
  int hid = j * 16 + l16;
  const short* ah = cond_hi + (size_t)rowA * 1024 + quad * 8;
  const short* al = cond_lo + (size_t)rowA * 1024 + quad * 8;
  f4v acc[4];
#pragma unroll
  for (int g = 0; g < 4; ++g) acc[g] = (f4v){0.f, 0.f, 0.f, 0.f};
#pragma unroll 2
  for (int kk = 0; kk < 32; ++kk) {
    s8v avh = *(const s8v*)(ah + kk * 32);
    s8v avl = *(const s8v*)(al + kk * 32);
#pragma unroll
    for (int g = 0; g < 4; ++g) {
      size_t off = ((size_t)(g * 64 + j) * 32 + kk) * 512 + (size_t)lane * 8;
      s8v bh = *(const s8v*)(WTc_hi + off);
      s8v bl = *(const s8v*)(WTc_lo + off);
      acc[g] = __builtin_amdgcn_mfma_f32_16x16x32_bf16(avh, bh, acc[g], 0, 0, 0);
      acc[g] = __builtin_amdgcn_mfma_f32_16x16x32_bf16(avh, bl, acc[g], 0, 0, 0);
      acc[g] = __builtin_amdgcn_mfma_f32_16x16x32_bf16(avl, bh, acc[g], 0, 0, 0);
    }
  }
#pragma unroll
  for (int g = 0; g < 4; ++g) {
    float vv = vec0[g * 1024 + hid];
#pragma unroll
    for (int p = 0; p < 4; ++p) {
      int r = rowC + p;
      const0[(size_t)r * G4 + g * 1024 + hid] = acc[g][p] + vv;
    }
  }
}

// ---------------- main persistent kernel --------------------------------------
__global__ __launch_bounds__(512) void lstm_main(
    const short* __restrict__ WT0, const short* __restrict__ WT1,
    const float* __restrict__ const0, const float* __restrict__ Wf,
    const float* __restrict__ b1vec, const short* __restrict__ WoFh,
    const short* __restrict__ WoFl, const float* __restrict__ bo,
    const float* __restrict__ sos, float* __restrict__ out,
    short* __restrict__ hbuf, u32* __restrict__ bar) {
  int tid = threadIdx.x;
  u32 xcc;
  asm volatile("s_getreg_b32 %0, hwreg(20, 0, 32)" : "=s"(xcc));
  xcc &= 7;
  __shared__ u32 sslot;
  if (tid == 0)
    sslot = __hip_atomic_fetch_add(&bar[xcc], 1u, __ATOMIC_RELAXED,
                                   __HIP_MEMORY_SCOPE_SYSTEM);
  __syncthreads();
  u32 jb = sslot;
  if (jb >= 32) return;          // surplus block on a full XCD
  u32* gbar = bar + 64 + (size_t)jb * 16;  // per-jb group counter (8 arrivals)

  int w = tid >> 6, lane = tid & 63;
  int g = w >> 1, half = w & 1;  // wave -> gate g, ntile-half
  int quad = lane >> 4, l16 = lane & 15;
  int quad8 = quad * 8;
  int x = (int)xcc;
  int row0 = (int)jb * 16;       // block's 16 rows (same rows on every XCD)
  int erow = tid >> 5;           // epilogue: row within block (0..15)
  int ecb  = (tid & 31) * 4;     // epilogue: col base within slice (0..124)
  int gr = row0 + erow;          // global row of epilogue cells

  __shared__ short Ast[16][1032];   // staged h0 (persists across phases/steps)
  __shared__ short Bst[16][1032];   // staged h1_prev
  __shared__ float accst[4][16][132];  // gate partials, padded stride
  __shared__ float lgl[16][34];
  __shared__ float curs[16][2];

  // step-invariant per-thread constants (epilogue cells: 1 row x 4 cols)
  float wf0v[4][4], wf1v[4][4], b1vv[4][4], c0vv[4][4];
#pragma unroll
  for (int g2 = 0; g2 < 4; ++g2)
#pragma unroll
    for (int cc = 0; cc < 4; ++cc) {
      int n = g2 * 1024 + x * 128 + ecb + cc;
      wf0v[g2][cc] = Wf[2 * n + 0];
      wf1v[g2][cc] = Wf[2 * n + 1];
      b1vv[g2][cc] = b1vec[n];
      c0vv[g2][cc] = const0[(size_t)gr * G4 + n];
    }
  size_t nb0[4], nb1[4];
#pragma unroll
  for (int j = 0; j < 4; ++j) {
    int nt = g * 64 + x * 8 + half * 4 + j;  // global ntile of this wave's j-th tile
    nb0[j] = (size_t)nt * 32;
    nb1[j] = (size_t)nt * 64;
  }
  float boA = (w == 0) ? bo[l16] : ((w == 1) ? bo[16 + l16] : bo[32]);
  float sos0 = sos[0], sos1 = sos[1];
  float c0s[4] = {0.f, 0.f, 0.f, 0.f};
  float c1s[4] = {0.f, 0.f, 0.f, 0.f};
  u64 sink = 0;
  u32 snum = 0;

  for (int s = 0; s < NSTEPS; ++s) {
    int bank_r = (s & 1) * 2048;
    int bank_w = ((s + 1) & 1) * 2048;
    s8v breg[4];

    // ================= Phase A: logits+cur (s-1) and layer-0 =================
    // Ast already holds h0_prev (staged in phase B of step s-1; bank match).
    if (s > 0)
      stage_issue(hbuf, row0, bank_r + 1024, tid, breg);  // h1_prev in flight

    // layer-0 gemm (Ast resident; overlaps with Bst fetch)
    {
      f4v acc[4];
#pragma unroll
      for (int j = 0; j < 4; ++j) acc[j] = (f4v){0.f, 0.f, 0.f, 0.f};
      if (s > 0) {
#pragma unroll 4
        for (int kk = 0; kk < 32; ++kk) {
          s8v av = *(const s8v*)&Ast[l16][quad8 + kk * 32];
#pragma unroll
          for (int j = 0; j < 4; ++j) {
            s8v bv = *(const s8v*)(WT0 + (nb0[j] + kk) * 512 + (size_t)lane * 8);
            acc[j] = __builtin_amdgcn_mfma_f32_16x16x32_bf16(av, bv, acc[j], 0, 0, 0);
          }
        }
      }
#pragma unroll
      for (int j = 0; j < 4; ++j)
#pragma unroll
        for (int p = 0; p < 4; ++p)
          accst[g][quad * 4 + p][(half * 4 + j) * 16 + l16] = acc[j][p];
    }
    if (s > 0) {
      asm volatile("s_waitcnt vmcnt(0)" ::: "memory");
      __builtin_amdgcn_sched_barrier(0);
      stage_write(Bst, tid, breg);
    }
    __syncthreads();
    if (s > 0 && w < 3) {  // logits: 3 waves, one Wo ntile each
      f4v la = {0.f, 0.f, 0.f, 0.f};
      const short* bh = WoFh + (size_t)w * 32 * 512 + (size_t)lane * 8;
      const short* bl = WoFl + (size_t)w * 32 * 512 + (size_t)lane * 8;
#pragma unroll 4
      for (int kk = 0; kk < 32; ++kk) {
        s8v av = *(const s8v*)&Bst[l16][quad8 + kk * 32];
        la = __builtin_amdgcn_mfma_f32_16x16x32_bf16(av, *(const s8v*)(bh + (size_t)kk * 512), la, 0, 0, 0);
        la = __builtin_amdgcn_mfma_f32_16x16x32_bf16(av, *(const s8v*)(bl + (size_t)kk * 512), la, 0, 0, 0);
      }
      int r0 = quad * 4;
#pragma unroll
      for (int p = 0; p < 4; ++p) {
        if (w == 0)      lgl[r0 + p][l16]      = la[p] + boA;
        else if (w == 1) lgl[r0 + p][16 + l16] = la[p] + boA;
        else if (l16 == 0) lgl[r0 + p][32]     = la[p] + boA;
      }
    }
    __syncthreads();
    if (s > 0) {
      if (tid < 16) {  // cur for row tid
        float note = (lgl[tid][0] > 0.0f) ? 1.0f : 0.0f;
        float mx = lgl[tid][1];
        int mi = 0;
        for (int v = 1; v < 32; ++v) {
          float t = lgl[tid][1 + v];
          if (t > mx) { mx = t; mi = v; }
        }
        curs[tid][0] = note;
        curs[tid][1] = (float)mi * (1.0f / 31.0f);
      }
      if (xcc == 0) {  // out write (XCD 0 only; 16*33 = 528 cells)
        for (int q = tid; q < 16 * NOUTC; q += 512) {
          int rl = q / NOUTC, chn = q - rl * NOUTC;
          int r = row0 + rl;
          out[((size_t)((r >> 6) * NOUTC + chn) * 64 + (r & 63)) * 128 + (s - 1)] =
              lgl[rl][chn];
        }
      }
    }
    __syncthreads();
    // layer-0 epilogue (all 512 threads; 1 row x 4 cols each)
    {
      float cu0v = (s == 0) ? sos0 : curs[erow][0];
      float cu1v = (s == 0) ? sos1 : curs[erow][1];
      f4v aI = *(const f4v*)&accst[0][erow][ecb];
      f4v aF = *(const f4v*)&accst[1][erow][ecb];
      f4v aG = *(const f4v*)&accst[2][erow][ecb];
      f4v aO = *(const f4v*)&accst[3][erow][ecb];
      union { u64 pk; short hv[4]; } u;
#pragma unroll
      for (int cc = 0; cc < 4; ++cc) {
        float gi = aI[cc] + c0vv[0][cc] + cu0v * wf0v[0][cc] + cu1v * wf1v[0][cc];
        float gf = aF[cc] + c0vv[1][cc] + cu0v * wf0v[1][cc] + cu1v * wf1v[1][cc];
        float gg = aG[cc] + c0vv[2][cc] + cu0v * wf0v[2][cc] + cu1v * wf1v[2][cc];
        float go = aO[cc] + c0vv[3][cc] + cu0v * wf0v[3][cc] + cu1v * wf1v[3][cc];
        float ccv = fsig(gf) * c0s[cc] + fsig(gi) * ftanh(gg);
        c0s[cc] = ccv;
        u.hv[cc] = f2bf(fsig(go) * ftanh(ccv));
      }
      u64* dst = (u64*)(hbuf + (size_t)gr * G4 + bank_w + x * 128 + ecb);
      sink ^= __hip_atomic_exchange(dst, u.pk, __ATOMIC_RELAXED,
                                    __HIP_MEMORY_SCOPE_SYSTEM);
    }
    ++snum; gridbar(gbar, snum * 8u);

    // ================= Phase B: layer-1 =================
    stage_issue(hbuf, row0, bank_w, tid, breg);  // h0_new (all cols, all XCDs)
    asm volatile("s_waitcnt vmcnt(0)" ::: "memory");
    __builtin_amdgcn_sched_barrier(0);
    stage_write(Ast, tid, breg);                 // persists into next step
    __syncthreads();
    {
      f4v acc[4];
#pragma unroll
      for (int j = 0; j < 4; ++j) acc[j] = (f4v){0.f, 0.f, 0.f, 0.f};
#pragma unroll 4
      for (int kk = 0; kk < 32; ++kk) {  // chain 1: h0_new @ Wih1
        s8v av = *(const s8v*)&Ast[l16][quad8 + kk * 32];
#pragma unroll
        for (int j = 0; j < 4; ++j) {
          s8v bv = *(const s8v*)(WT1 + (nb1[j] + kk) * 512 + (size_t)lane * 8);
          acc[j] = __builtin_amdgcn_mfma_f32_16x16x32_bf16(av, bv, acc[j], 0, 0, 0);
        }
      }
      if (s > 0) {
#pragma unroll 4
        for (int kk = 0; kk < 32; ++kk) {  // chain 2: h1_prev @ Whh1
          s8v av = *(const s8v*)&Bst[l16][quad8 + kk * 32];
#pragma unroll
          for (int j = 0; j < 4; ++j) {
            s8v bv = *(const s8v*)(WT1 + (nb1[j] + 32 + kk) * 512 + (size_t)lane * 8);
            acc[j] = __builtin_amdgcn_mfma_f32_16x16x32_bf16(av, bv, acc[j], 0, 0, 0);
          }
        }
      }
#pragma unroll
      for (int j = 0; j < 4; ++j)
#pragma unroll
        for (int p = 0; p < 4; ++p)
          accst[g][quad * 4 + p][(half * 4 + j) * 16 + l16] = acc[j][p];
    }
    __syncthreads();
    // layer-1 epilogue
    {
      f4v aI = *(const f4v*)&accst[0][erow][ecb];
      f4v aF = *(const f4v*)&accst[1][erow][ecb];
      f4v aG = *(const f4v*)&accst[2][erow][ecb];
      f4v aO = *(const f4v*)&accst[3][erow][ecb];
      union { u64 pk; short hv[4]; } u;
#pragma unroll
      for (int cc = 0; cc < 4; ++cc) {
        float gi = aI[cc] + b1vv[0][cc];
        float gf = aF[cc] + b1vv[1][cc];
        float gg = aG[cc] + b1vv[2][cc];
        float go = aO[cc] + b1vv[3][cc];
        float ccv = fsig(gf) * c1s[cc] + fsig(gi) * ftanh(gg);
        c1s[cc] = ccv;
        u.hv[cc] = f2bf(fsig(go) * ftanh(ccv));
      }
      u64* dst = (u64*)(hbuf + (size_t)gr * G4 + bank_w + 1024 + x * 128 + ecb);
      sink ^= __hip_atomic_exchange(dst, u.pk, __ATOMIC_RELAXED,
                                    __HIP_MEMORY_SCOPE_SYSTEM);
    }
    ++snum; gridbar(gbar, snum * 8u);
  }

  // final logits for s=127 (h1(127) sits in bank 0, +1024)
  if (xcc == 0) {
    s8v breg[4];
    stage_issue(hbuf, row0, 0 + 1024, tid, breg);
    asm volatile("s_waitcnt vmcnt(0)" ::: "memory");
    __builtin_amdgcn_sched_barrier(0);
    stage_write(Bst, tid, breg);
    __syncthreads();
    if (w < 3) {
      f4v la = {0.f, 0.f, 0.f, 0.f};
      const short* bh = WoFh + (size_t)w * 32 * 512 + (size_t)lane * 8;
      const short* bl = WoFl + (size_t)w * 32 * 512 + (size_t)lane * 8;
#pragma unroll 4
      for (int kk = 0; kk < 32; ++kk) {
        s8v av = *(const s8v*)&Bst[l16][quad8 + kk * 32];
        la = __builtin_amdgcn_mfma_f32_16x16x32_bf16(av, *(const s8v*)(bh + (size_t)kk * 512), la, 0, 0, 0);
        la = __builtin_amdgcn_mfma_f32_16x16x32_bf16(av, *(const s8v*)(bl + (size_t)kk * 512), la, 0, 0, 0);
      }
      int r0 = quad * 4;
#pragma unroll
      for (int p = 0; p < 4; ++p) {
        if (w == 0)      lgl[r0 + p][l16]      = la[p] + boA;
        else if (w == 1) lgl[r0 + p][16 + l16] = la[p] + boA;
        else if (l16 == 0) lgl[r0 + p][32]     = la[p] + boA;
      }
    }
    __syncthreads();
    for (int q = tid; q < 16 * NOUTC; q += 512) {
      int rl = q / NOUTC, chn = q - rl * NOUTC;
      int r = row0 + rl;
      out[((size_t)((r >> 6) * NOUTC + chn) * 64 + (r & 63)) * 128 + (NSTEPS - 1)] =
          lgl[rl][chn];
    }
  }
  asm volatile("" :: "v"(sink));  // keep returning-form atomics live
}

// ---------------- host launch -------------------------------------------------
extern "C" void kernel_launch(void* const* d_in, const int* in_sizes, int n_in,
                              void* d_out, int out_size, void* d_ws, size_t ws_size,
                              hipStream_t stream) {
  (void)in_sizes; (void)n_in; (void)out_size; (void)ws_size;
  const float* x    = (const float*)d_in[0];
  const float* sos  = (const float*)d_in[1];
  const float* Wc   = (const float*)d_in[2];
  const float* bc   = (const float*)d_in[3];
  const float* Wi   = (const float*)d_in[4];
  const float* bi   = (const float*)d_in[5];
  const float* Wih0 = (const float*)d_in[6];
  const float* Whh0 = (const float*)d_in[7];
  const float* bih0 = (const float*)d_in[8];
  const float* bhh0 = (const float*)d_in[9];
  const float* Wih1 = (const float*)d_in[10];
  const float* Whh1 = (const float*)d_in[11];
  const float* bih1 = (const float*)d_in[12];
  const float* bhh1 = (const float*)d_in[13];
  const float* Wo   = (const float*)d_in[14];
  const float* bo   = (const float*)d_in[15];
  float* out = (float*)d_out;

  char* p = (char*)d_ws;
  short* WT0    = (short*)p; p += (size_t)256 * 32 * 512 * 2;  // 8 MB
  short* WT1    = (short*)p; p += (size_t)256 * 64 * 512 * 2;  // 16 MB
  short* WTc_hi = (short*)p; p += (size_t)256 * 32 * 512 * 2;  // 8 MB
  short* WTc_lo = (short*)p; p += (size_t)256 * 32 * 512 * 2;  // 8 MB
  float* const0 = (float*)p; p += (size_t)512 * 4096 * 4;      // 8 MB
  short* hbuf   = (short*)p; p += (size_t)512 * 4096 * 2;      // 4 MB
  short* cond_hi= (short*)p; p += (size_t)512 * 1024 * 2;      // 1 MB
  short* cond_lo= (short*)p; p += (size_t)512 * 1024 * 2;      // 1 MB
  float* vec0   = (float*)p; p += 4096 * 4;
  float* Wf     = (float*)p; p += 4096 * 2 * 4;
  float* b1vec  = (float*)p; p += 4096 * 4;
  short* WoFh   = (short*)p; p += (size_t)48 * 1024 * 2;       // 96 KB
  short* WoFl   = (short*)p; p += (size_t)48 * 1024 * 2;       // 96 KB
  u32*   bar    = (u32*)p;   p += 4096;  // [0..7] XCD claims; [64+jb*16] group bars

  hipMemsetAsync(bar, 0, 4096, stream);

  transpose_frag_kernel<<<1024, 256, 0, stream>>>(Whh0, WT0, nullptr, 32, 0);
  transpose_frag_kernel<<<1024, 256, 0, stream>>>(Wih1, WT1, nullptr, 64, 0);
  transpose_frag_kernel<<<1024, 256, 0, stream>>>(Whh1, WT1, nullptr, 64, 32);
  transpose_frag_kernel<<<1024, 256, 0, stream>>>(Wih0 + (size_t)1024 * 4096,
                                                  WTc_hi, WTc_lo, 32, 0);
  cond_kernel<<<256, 256, 0, stream>>>(x, Wc, bc, cond_hi, cond_lo);
  vecs_kernel<<<16, 256, 0, stream>>>(Wih0, bi, Wi, bih0, bhh0, bih1, bhh1,
                                      vec0, Wf, b1vec);
  wof_kernel<<<96, 64, 0, stream>>>(Wo, WoFh, WoFl);
  const0_kernel<<<256, 512, 0, stream>>>(cond_hi, cond_lo, WTc_hi, WTc_lo,
                                         vec0, const0);
  lstm_main<<<2048, 512, 0, stream>>>(WT0, WT1, const0, Wf, b1vec, WoFh, WoFl,
                                      bo, sos, out, hbuf, bar);
}